// Round 5
// baseline (5115.318 us; speedup 1.0000x reference)
//
#include <hip/hip_runtime.h>
#include <math.h>

#define B    128
#define T    20
#define TD   19      // Tdec
#define V    10000
#define D    1024
#define E    1024
#define A_DIM 1024
#define F    2048
#define NR   36
#define BD   (B * D)  // 131072

typedef __attribute__((ext_vector_type(8))) short bf16x8;
typedef __attribute__((ext_vector_type(4))) float f32x4;

__device__ __forceinline__ float sigm(float x) { return 1.f / (1.f + __expf(-x)); }

__device__ __forceinline__ unsigned short f2bf(float f) {
    union { float f; unsigned u; } x; x.f = f;
    unsigned r = x.u + 0x7fffu + ((x.u >> 16) & 1u);
    return (unsigned short)(r >> 16);
}
__device__ __forceinline__ float bf2f(unsigned short u) {
    union { float f; unsigned u; } x; x.u = ((unsigned)u) << 16; return x.f;
}
__device__ __forceinline__ bf16x8 as_bf(uint4 v) {
    union { uint4 u; bf16x8 b; } x; x.u = v; return x.b;
}
__device__ __forceinline__ uint4 pack8(const float* __restrict__ src) {
    float4 a = *(const float4*)src, b = *(const float4*)(src + 4);
    union { unsigned short u[8]; uint4 v; } p;
    p.u[0] = f2bf(a.x); p.u[1] = f2bf(a.y); p.u[2] = f2bf(a.z); p.u[3] = f2bf(a.w);
    p.u[4] = f2bf(b.x); p.u[5] = f2bf(b.y); p.u[6] = f2bf(b.z); p.u[7] = f2bf(b.w);
    return p.v;
}

// ---------------------------------------------------------------------------
// Sort (stable descending by sizes), seqs/order outputs, active counts
// ---------------------------------------------------------------------------
__global__ void k_sort_init(const int* __restrict__ sizes,
                            const int* __restrict__ sequences,
                            int* __restrict__ order,
                            int* __restrict__ active,
                            int* __restrict__ seqs_s,
                            float* __restrict__ out)
{
    int tid = threadIdx.x;                // 128 threads
    __shared__ int s_sizes[B];
    __shared__ int s_dl[B];
    s_sizes[tid] = sizes[tid];
    __syncthreads();
    int si = s_sizes[tid];
    int rank = 0;
    for (int j = 0; j < B; ++j) {
        int sj = s_sizes[j];
        if (sj > si || (sj == si && j < tid)) rank++;
    }
    order[rank] = tid;
    __syncthreads();
    int ob = order[tid];
    int dl = s_sizes[ob] - 1;
    s_dl[tid] = dl;
    for (int tt = 0; tt < T; ++tt) {
        int sq = sequences[ob * T + tt];
        seqs_s[tid * T + tt] = sq;
        out[(size_t)B * TD * V + tid * T + tt] = (float)sq;
    }
    out[(size_t)B * TD * V + B * T + tid] = (float)ob;
    __syncthreads();
    if (tid < TD) {
        int c = 0;
        for (int b = 0; b < B; ++b) c += (s_dl[b] > tid) ? 1 : 0;
        active[tid] = c;
    }
    if (tid == 0) out[(size_t)B * TD * V + B * T + B] = 0.f;   // loss accumulator
}

__global__ void k_zero(float* __restrict__ p, int n) {
    int i = blockIdx.x * 256 + threadIdx.x;
    if (i < n) p[i] = 0.f;
}

// weight f32 -> bf16, rows concatenated [s1 row (K1) | s2 row (K2)]
// s2 == nullptr with K2 > 0: zero-pad the K2 region.
// il == 1: gate-interleave row permutation: src row = (r&3)*1024 + (r>>2)
__global__ void k_w2bf(const float* __restrict__ s1, int K1,
                       const float* __restrict__ s2, int K2,
                       unsigned short* __restrict__ dst, long total /*granules*/,
                       int il)
{
    long g = (long)blockIdx.x * 256 + threadIdx.x;
    if (g >= total) return;
    int Kt = K1 + K2;
    int gpr = Kt >> 3;
    int row = (int)(g / gpr);
    int k8 = (int)(g % gpr) << 3;
    if (k8 >= K1 && !s2) {
        uint4 z{};
        *(uint4*)(dst + ((size_t)g << 3)) = z;
        return;
    }
    int srow = il ? ((row & 3) * 1024 + (row >> 2)) : row;
    const float* src = (k8 < K1) ? (s1 + (size_t)srow * K1 + k8)
                                 : (s2 + (size_t)srow * K2 + (k8 - K1));
    *(uint4*)(dst + ((size_t)g << 3)) = pack8(src);
}

// feats (sorted by order) -> bf16 [4608 x 2048]
__global__ void k_feats2bf(const float* __restrict__ feats, const int* __restrict__ order,
                           unsigned short* __restrict__ dst)
{
    long g = (long)blockIdx.x * 256 + threadIdx.x;   // 4608*256 granules
    int row = (int)(g >> 8);
    int k8 = ((int)g & 255) << 3;
    int b = row / NR, r = row - b * NR;
    const float* src = feats + ((size_t)order[b] * NR + r) * F + k8;
    *(uint4*)(dst + (size_t)row * F + k8) = pack8(src);
}

// featsAvg -> bf16 directly into xtd slot [1024,3072)
__global__ void k_favg(const float* __restrict__ feats, const int* __restrict__ order,
                       unsigned short* __restrict__ xtd)
{
    int idx = blockIdx.x * 256 + threadIdx.x;   // B*F = 262144
    int b = idx >> 11, f = idx & 2047;
    const float* base = feats + (size_t)order[b] * NR * F + f;
    float s = 0.f;
#pragma unroll
    for (int r = 0; r < NR; ++r) s += base[(size_t)r * F];
    xtd[(size_t)b * 5120 + 1024 + f] = f2bf(s * (1.f / NR));
}

// embeddings (sorted) -> bf16 [B x TD x 1024]
__global__ void k_emb2bf(const float* __restrict__ emb, const int* __restrict__ seqs_s,
                         unsigned short* __restrict__ embs_bf)
{
    long g = (long)blockIdx.x * 256 + threadIdx.x;  // B*TD*128 granules
    if (g >= (long)B * TD * 128) return;
    int b = (int)(g / (TD * 128));
    int rem = (int)(g - (long)b * (TD * 128));
    int t = rem >> 7, e8 = (rem & 127) << 3;
    const float* src = emb + (size_t)seqs_s[b * T + t] * E + e8;
    *(uint4*)(embs_bf + (((size_t)(b * TD + t)) << 10) + e8) = pack8(src);
}

// copy embs_bf[:,t,:] into xtd emb slot [3072,4096)  (used once, t=0)
__global__ void k_embslot(const unsigned short* __restrict__ embs_bf,
                          unsigned short* __restrict__ xtd, int t)
{
    int g = blockIdx.x * 256 + threadIdx.x;  // B*128 = 16384
    int b = g >> 7, e8 = (g & 127) << 3;
    *(uint4*)(xtd + (size_t)b * 5120 + 3072 + e8) =
        *(const uint4*)(embs_bf + (((size_t)(b * TD + t)) << 10) + e8);
}

// interleaved combined bias: dst[j*4+g] = bi[g*1024+j] + bh[g*1024+j]
// i >= 4096 (if n > 4096): dst[i] = extra[i-4096]
__global__ void k_biasint(const float* __restrict__ bi, const float* __restrict__ bh,
                          const float* __restrict__ extra, float* __restrict__ dst, int n)
{
    int i = blockIdx.x * 256 + threadIdx.x;
    if (i >= n) return;
    if (i < 4096) {
        int j = i >> 2, g = i & 3;
        dst[i] = bi[g * 1024 + j] + bh[g * 1024 + j];
    } else {
        dst[i] = extra[i - 4096];
    }
}

// ---------------------------------------------------------------------------
// Shared GEMM core: C[m][n] = sum_k A[m][k]*W[n][k], tile M=128 x N=32, BK=64,
// 256 threads (4 waves).
// KEY FACTS:
//  * A is wave-private in this decomposition -> A fragments stay in REGISTERS
//    (the old LDS round-trip was an identity). Only W goes through LDS
//    (1 uint4/thread/tile; each wave stages 8 rows, all waves read all).
//  * 4-deep prefetch with STATICALLY-NAMED register sets (rule #20), loop
//    unrolled x4 (ntile % 4 == 0 for all K used: 80/64/32/16).
//  * ONE barrier per tile: stash(t)->buf(t&1) is protected by tile t-1's
//    barrier (compute(t-2) reads of that buffer finished before it).
//  * sched_barrier(0) after s_barrier pins LDS reads below the barrier.
// smem: 2 buffers x 2048 ushort = 8 KB.
// ---------------------------------------------------------------------------
#define GC_LOAD(s) do { \
    rA##s##_0 = *(const uint4*)ap0; ap0 += 64; \
    rA##s##_1 = *(const uint4*)ap1; ap1 += 64; \
    rA##s##_2 = *(const uint4*)ap2; ap2 += 64; \
    rA##s##_3 = *(const uint4*)ap3; ap3 += 64; \
    rW##s = *(const uint4*)wp; wp += 64; \
} while (0)

#define GC_COMPUTE(s, buf) do { \
    unsigned short* Ws_ = smem + (buf) * 2048; \
    bf16x8 b0a = *(const bf16x8*)(Ws_ + 0 * 512 + l * 8); \
    bf16x8 b1a = *(const bf16x8*)(Ws_ + 2 * 512 + l * 8); \
    acc[0][0] = __builtin_amdgcn_mfma_f32_16x16x32_bf16(as_bf(rA##s##_0), b0a, acc[0][0], 0, 0, 0); \
    acc[0][1] = __builtin_amdgcn_mfma_f32_16x16x32_bf16(as_bf(rA##s##_0), b1a, acc[0][1], 0, 0, 0); \
    acc[1][0] = __builtin_amdgcn_mfma_f32_16x16x32_bf16(as_bf(rA##s##_2), b0a, acc[1][0], 0, 0, 0); \
    acc[1][1] = __builtin_amdgcn_mfma_f32_16x16x32_bf16(as_bf(rA##s##_2), b1a, acc[1][1], 0, 0, 0); \
    bf16x8 b0b = *(const bf16x8*)(Ws_ + 1 * 512 + l * 8); \
    bf16x8 b1b = *(const bf16x8*)(Ws_ + 3 * 512 + l * 8); \
    acc[0][0] = __builtin_amdgcn_mfma_f32_16x16x32_bf16(as_bf(rA##s##_1), b0b, acc[0][0], 0, 0, 0); \
    acc[0][1] = __builtin_amdgcn_mfma_f32_16x16x32_bf16(as_bf(rA##s##_1), b1b, acc[0][1], 0, 0, 0); \
    acc[1][0] = __builtin_amdgcn_mfma_f32_16x16x32_bf16(as_bf(rA##s##_3), b0b, acc[1][0], 0, 0, 0); \
    acc[1][1] = __builtin_amdgcn_mfma_f32_16x16x32_bf16(as_bf(rA##s##_3), b1b, acc[1][1], 0, 0, 0); \
} while (0)

#define GC_TILE(s, buf, more) do { \
    *(uint4*)(smem + (buf) * 2048 + w * 512 + l * 8) = rW##s; \
    asm volatile("s_waitcnt lgkmcnt(0)" ::: "memory"); \
    __builtin_amdgcn_s_barrier(); \
    __builtin_amdgcn_sched_barrier(0); \
    GC_COMPUTE(s, buf); \
    if (more) GC_LOAD(s); \
} while (0)

__device__ __forceinline__ void gemm_core(
    const unsigned short* __restrict__ A, int lda,
    const unsigned short* __restrict__ W, int K, int N,
    unsigned short* __restrict__ smem,
    int bm, int bn, f32x4 (&acc)[2][2])
{
    int tid = threadIdx.x, l = tid & 63, w = tid >> 6;
    int rsel = l & 15, ksel = (l >> 4) * 8;

    const unsigned short* ap0 = A + (size_t)(bm + (2 * w) * 16 + rsel) * lda + ksel;
    const unsigned short* ap1 = ap0 + 32;
    const unsigned short* ap2 = A + (size_t)(bm + (2 * w + 1) * 16 + rsel) * lda + ksel;
    const unsigned short* ap3 = ap2 + 32;

    int nt_w = w >> 1, wsub = w & 1;
    int nr = bn + nt_w * 16 + rsel; if (nr >= N) nr = N - 1;
    const unsigned short* wp = W + (size_t)nr * K + wsub * 32 + ksel;
    int ntile = K >> 6;     // divisible by 4 for all K used here

    uint4 rA0_0, rA0_1, rA0_2, rA0_3, rW0;
    uint4 rA1_0, rA1_1, rA1_2, rA1_3, rW1;
    uint4 rA2_0, rA2_1, rA2_2, rA2_3, rW2;
    uint4 rA3_0, rA3_1, rA3_2, rA3_3, rW3;

    GC_LOAD(0); GC_LOAD(1); GC_LOAD(2); GC_LOAD(3);   // tiles 0..3 in flight
    for (int t = 0; t < ntile; t += 4) {
        int more = (t + 4 < ntile);
        GC_TILE(0, 0, more);    // tile t+0 -> buf0
        GC_TILE(1, 1, more);    // tile t+1 -> buf1
        GC_TILE(2, 0, more);    // tile t+2 -> buf0
        GC_TILE(3, 1, more);    // tile t+3 -> buf1
    }
}

// ---------------------------------------------------------------------------
// Plain MFMA GEMM (modes 0 / 1 / 3)
//   0: store C = acc + bias
//   1: batched ARNet loss (no store): per blockIdx.y (= t-1), act=actp[y];
//      sum (acc+bias-sub)^2 over (row&127)<act -> atomicAdd(lossp,*0.005/act)
//   3: batched pred store, grid (nPanels, TD): panel-fast launch order means
//      concurrent blocks share one A t-tile (L2-resident) and stream W;
//      row=t*128+b -> out[b][t][col], zero if b>=actp[t]
// ---------------------------------------------------------------------------
__global__ __launch_bounds__(256)
void k_gemm(const unsigned short* __restrict__ A, int lda,
            const unsigned short* __restrict__ W, int K,
            const float* __restrict__ bias,
            float* __restrict__ C, int ldc, int N,
            int mode, const float* __restrict__ sub, const int* __restrict__ actp,
            float* __restrict__ lossp)
{
    __shared__ __align__(16) unsigned short smem[2 * 2048];   // 8 KB
    __shared__ float ps[4];

    int bn = blockIdx.x * 32, bm = blockIdx.y * 128;
    int tid = threadIdx.x, l = tid & 63, w = tid >> 6;

    f32x4 acc[2][2] = {};
    gemm_core(A, lda, W, K, N, smem, bm, bn, acc);

    int rg4 = (l >> 4) * 4, cc = l & 15;
    if (mode == 1) {
        int act = actp[blockIdx.y];
        float s = 0.f;
#pragma unroll
        for (int mi = 0; mi < 2; ++mi) {
            int mt = 2 * w + mi;
#pragma unroll
            for (int ni = 0; ni < 2; ++ni) {
                int col = bn + ni * 16 + cc;
                float bb = bias[col];
#pragma unroll
                for (int rg = 0; rg < 4; ++rg) {
                    int row = bm + mt * 16 + rg4 + rg;
                    float v = acc[mi][ni][rg] + bb - sub[(size_t)row * 1024 + col];
                    if ((row & 127) < act) s += v * v;
                }
            }
        }
        for (int o = 32; o > 0; o >>= 1) s += __shfl_down(s, o, 64);
        if (l == 0) ps[w] = s;
        __syncthreads();
        if (tid == 0) {
            float tot = ps[0] + ps[1] + ps[2] + ps[3];
            atomicAdd(lossp, tot * (0.005f / (float)act));
        }
        return;
    }

    if (mode == 3) {
#pragma unroll
        for (int mi = 0; mi < 2; ++mi) {
            int mt = 2 * w + mi;
#pragma unroll
            for (int ni = 0; ni < 2; ++ni) {
                int col = bn + ni * 16 + cc;
                if (col >= N) continue;
                float bb = bias[col];
#pragma unroll
                for (int rg = 0; rg < 4; ++rg) {
                    int row = bm + mt * 16 + rg4 + rg;
                    int tt = row >> 7, b = row & 127;
                    float v = acc[mi][ni][rg] + bb;
                    if (b >= actp[tt]) v = 0.f;
                    C[(size_t)b * ((size_t)TD * V) + (size_t)tt * V + col] = v;
                }
            }
        }
        return;
    }

#pragma unroll
    for (int mi = 0; mi < 2; ++mi) {
        int mt = 2 * w + mi;
#pragma unroll
        for (int ni = 0; ni < 2; ++ni) {
            int col = bn + ni * 16 + cc;
            if (col >= N) continue;
            float bb = bias[col];
#pragma unroll
            for (int rg = 0; rg < 4; ++rg) {
                int row = bm + mt * 16 + rg4 + rg;
                C[(size_t)row * ldc + col] = acc[mi][ni][rg] + bb;
            }
        }
    }
}

// ---------------------------------------------------------------------------
// Fused gate-GEMM + LSTM pointwise. W rows are gate-interleaved (r'=j*4+g) so
// block bn<NL owns all 4 gates of units [bn/4, bn/4+8). Epilogue exchanges
// gates via LDS and applies the LSTM update + bf16 slot stores in-block.
// Blocks with bn>=NL store acc+bias to C2 (h1a path of the comb GEMM).
// Optional emb-slot prefetch for the next timestep (lg GEMM only).
// ---------------------------------------------------------------------------
__global__ __launch_bounds__(256)
void k_gemm_lstm(const unsigned short* __restrict__ A, int lda,
                 const unsigned short* __restrict__ W, int K,
                 const float* __restrict__ biasI, int NL, int N,
                 float* __restrict__ h, float* __restrict__ c,
                 const int* __restrict__ actp,
                 float* __restrict__ prevh,
                 unsigned short* __restrict__ s1, int ld1,
                 unsigned short* __restrict__ s2, int ld2,
                 unsigned short* __restrict__ s3, int ld3,
                 float* __restrict__ C2,
                 const unsigned short* __restrict__ embs_bf,
                 unsigned short* __restrict__ xtd_emb, int tnext)
{
    __shared__ __align__(16) unsigned short smem[8192];   // 16 KB (core uses 8 KB; Ls 16 KB)

    int tid = threadIdx.x, l = tid & 63, w = tid >> 6;
    int bn = blockIdx.x * 32;

    f32x4 acc[2][2] = {};
    gemm_core(A, lda, W, K, N, smem, 0, bn, acc);

    int rg4 = (l >> 4) * 4, cc = l & 15;

    if (bn >= NL) {
        // plain f32 store (h1a): C2 is [128 x (N-NL)]
        int ldc2 = N - NL;
#pragma unroll
        for (int mi = 0; mi < 2; ++mi) {
            int mt = 2 * w + mi;
#pragma unroll
            for (int ni = 0; ni < 2; ++ni) {
                int col = bn + ni * 16 + cc;
                float bb = biasI[col];
#pragma unroll
                for (int rg = 0; rg < 4; ++rg) {
                    int row = mt * 16 + rg4 + rg;
                    C2[(size_t)row * ldc2 + (col - NL)] = acc[mi][ni][rg] + bb;
                }
            }
        }
        return;
    }

    // stash gates (acc + bias) into LDS: Ls[row][col_local]
    __syncthreads();                 // waves may be past the last core barrier
    float* Ls = (float*)smem;        // 128*32 f32 = 16 KB
#pragma unroll
    for (int mi = 0; mi < 2; ++mi) {
        int mt = 2 * w + mi;
#pragma unroll
        for (int ni = 0; ni < 2; ++ni) {
            int col = bn + ni * 16 + cc;
            float bb = biasI[col];
#pragma unroll
            for (int rg = 0; rg < 4; ++rg) {
                int row = mt * 16 + rg4 + rg;
                Ls[row * 32 + (col - bn)] = acc[mi][ni][rg] + bb;
            }
        }
    }
    __syncthreads();

    int act = *actp;
    int j0 = bn >> 2;
    for (int e = tid; e < 128 * 8; e += 256) {
        int row = e >> 3, jl = e & 7;
        if (row < act) {
            const float* g = Ls + row * 32 + jl * 4;     // i,f,g,o
            int j = j0 + jl;
            size_t ix = (size_t)row * 1024 + j;
            if (prevh) prevh[ix] = h[ix];
            float c2v = sigm(g[1]) * c[ix] + sigm(g[0]) * tanhf(g[2]);
            c[ix] = c2v;
            float hv = sigm(g[3]) * tanhf(c2v);
            h[ix] = hv;
            unsigned short hb = f2bf(hv);
            if (s1) s1[(size_t)row * ld1 + j] = hb;
            if (s2) s2[(size_t)row * ld2 + j] = hb;
            if (s3) s3[(size_t)row * ld3 + j] = hb;
        }
    }

    // folded emb-slot prefetch for next timestep (lg GEMM, all 128 blocks)
    if (embs_bf && tid < 128) {
        int gI = blockIdx.x * 128 + tid;     // 128*128 = 16384 granules
        int be = gI >> 7, e8 = (gI & 127) << 3;
        *(uint4*)(xtd_emb + (size_t)be * 5120 + 3072 + e8) =
            *(const uint4*)(embs_bf + (((size_t)(be * TD + tnext)) << 10) + e8);
    }
}

// attention: e = relu(h1a + img_att).aw_w + aw_b ; softmax over 36 ;
// awe = alpha^T feats_bf -> bf16 into xlg slot [0,2048)
__global__ __launch_bounds__(256)
void k_attn(const float* __restrict__ h1a, int ldh, const float* __restrict__ img_att,
            const float* __restrict__ aw_w, const float* __restrict__ aw_b,
            const unsigned short* __restrict__ feats_bf,
            unsigned short* __restrict__ xlg)
{
    int b = blockIdx.x;
    int tid = threadIdx.x;
    __shared__ float sh[A_DIM];
    __shared__ float se[NR];
    for (int i = tid; i < A_DIM; i += 256) sh[i] = h1a[(size_t)b * ldh + i];
    __syncthreads();
    int wid = tid >> 6, lane = tid & 63;
    for (int r = wid; r < NR; r += 4) {
        const float* row = img_att + ((size_t)b * NR + r) * A_DIM;
        float s = 0.f;
        for (int a = lane; a < A_DIM; a += 64)
            s += fmaxf(sh[a] + row[a], 0.f) * aw_w[a];
        for (int off = 32; off > 0; off >>= 1) s += __shfl_down(s, off, 64);
        if (lane == 0) se[r] = s + aw_b[0];
    }
    __syncthreads();
    if (tid == 0) {
        float m = se[0];
        for (int r = 1; r < NR; ++r) m = fmaxf(m, se[r]);
        float ssum = 0.f;
        for (int r = 0; r < NR; ++r) { float ex = __expf(se[r] - m); se[r] = ex; ssum += ex; }
        float inv = 1.f / ssum;
        for (int r = 0; r < NR; ++r) se[r] *= inv;
    }
    __syncthreads();
    // awe: each thread owns 8 consecutive f (vector loads; r-order preserved)
    int f8 = tid << 3;                                   // 256*8 = 2048 = F
    const unsigned short* fb = feats_bf + (size_t)b * NR * F + f8;
    float s[8] = {};
    for (int r = 0; r < NR; ++r) {
        bf16x8 v = *(const bf16x8*)(fb + (size_t)r * F);
        float a = se[r];
#pragma unroll
        for (int q = 0; q < 8; ++q)
            s[q] += a * bf2f(((const unsigned short*)&v)[q]);
    }
    union { unsigned short u[8]; uint4 v4; } pk;
#pragma unroll
    for (int q = 0; q < 8; ++q) pk.u[q] = f2bf(s[q]);
    *(uint4*)(xlg + (size_t)b * 4096 + f8) = pk.v4;
}

// ---------------------------------------------------------------------------
extern "C" void kernel_launch(void* const* d_in, const int* in_sizes, int n_in,
                              void* d_out, int out_size, void* d_ws, size_t ws_size,
                              hipStream_t stream)
{
    const float* feats     = (const float*)d_in[0];
    const int*   sequences = (const int*)d_in[1];
    const int*   sizes     = (const int*)d_in[2];
    const float* emb       = (const float*)d_in[3];
    const float* td_wi = (const float*)d_in[4];
    const float* td_wh = (const float*)d_in[5];
    const float* td_bi = (const float*)d_in[6];
    const float* td_bh = (const float*)d_in[7];
    const float* lg_wi = (const float*)d_in[8];
    const float* lg_wh = (const float*)d_in[9];
    const float* lg_bi = (const float*)d_in[10];
    const float* lg_bh = (const float*)d_in[11];
    const float* ar_wi = (const float*)d_in[12];
    const float* ar_wh = (const float*)d_in[13];
    const float* ar_bi = (const float*)d_in[14];
    const float* ar_bh = (const float*)d_in[15];
    const float* arl_w = (const float*)d_in[16];
    const float* arl_b = (const float*)d_in[17];
    const float* out_w = (const float*)d_in[18];
    const float* out_b = (const float*)d_in[19];
    const float* af_w  = (const float*)d_in[20];
    const float* af_b  = (const float*)d_in[21];
    const float* ad_w  = (const float*)d_in[22];
    const float* ad_b  = (const float*)d_in[23];
    const float* aw_w  = (const float*)d_in[24];
    const float* aw_b  = (const float*)d_in[25];
    float* out = (float*)d_out;

    // ---- workspace carve (floats; every region multiple of 4 floats) ----
    float* ws = (float*)d_ws;
    size_t off = 0;
    auto alloc = [&](size_t n) { float* p = ws + off; off += n; return p; };
    // zero region: 6 f32 states + xtd + xlg + xar (contiguous)
    float* h1   = alloc((size_t)BD);
    float* c1   = alloc((size_t)BD);
    float* h2   = alloc((size_t)BD);
    float* c2   = alloc((size_t)BD);
    float* arh  = alloc((size_t)BD);
    float* arc  = alloc((size_t)BD);
    unsigned short* xtd = (unsigned short*)alloc((size_t)B * 5120 / 2);
    unsigned short* xlg = (unsigned short*)alloc((size_t)B * 4096 / 2);
    unsigned short* xar = (unsigned short*)alloc((size_t)B * 2048 / 2);
    int zero_n = 6 * BD + (B * 5120 + B * 4096 + B * 2048) / 2;  // 1,507,328
    // rest
    float* h1a       = alloc((size_t)B * A_DIM);
    float* prevh_all = alloc((size_t)(TD - 1) * BD);     // f32 h1 history (t=1..18)
    float* img_att   = alloc((size_t)B * NR * A_DIM);
    float* bias_td   = alloc(4096);
    float* bias_lg   = alloc(4096);
    float* bias_comb = alloc(5120);
    unsigned short* embs_bf  = (unsigned short*)alloc((size_t)B * TD * E / 2);
    unsigned short* feats_bf = (unsigned short*)alloc((size_t)B * NR * F / 2);
    unsigned short* Hout     = (unsigned short*)alloc((size_t)TD * BD / 2);       // h2 history
    unsigned short* Arout    = (unsigned short*)alloc((size_t)(TD - 1) * BD / 2); // arh history
    unsigned short* Wtd  = (unsigned short*)alloc((size_t)4096 * 5120 / 2);
    unsigned short* Wlg  = (unsigned short*)alloc((size_t)4096 * 4096 / 2);
    unsigned short* Wcomb = (unsigned short*)alloc((size_t)5120 * 2048 / 2);  // [War-il | Wad-pad]
    unsigned short* Wout = (unsigned short*)alloc((size_t)10048 * 1024 / 2); // V padded to panel
    unsigned short* Warl = (unsigned short*)alloc((size_t)1024 * 1024 / 2);
    unsigned short* Waf  = (unsigned short*)alloc((size_t)1024 * 2048 / 2);
    int* ip     = (int*)(ws + off);
    int* order  = ip; ip += B;
    int* active = ip; ip += TD + 1;
    int* seqs_s = ip; ip += B * T;

    float* loss_ptr = out + (size_t)B * TD * V + B * T + B;

    // ---- prologue ----
    k_sort_init<<<1, B, 0, stream>>>(sizes, sequences, order, active, seqs_s, out);
    k_zero<<<(zero_n + 255) / 256, 256, 0, stream>>>(h1, zero_n);
    k_favg<<<1024, 256, 0, stream>>>(feats, order, xtd);
    k_emb2bf<<<(B * TD * 128 + 255) / 256, 256, 0, stream>>>(emb, seqs_s, embs_bf);
    k_feats2bf<<<4608, 256, 0, stream>>>(feats, order, feats_bf);
    k_w2bf<<<10240, 256, 0, stream>>>(td_wi, 4096, td_wh, 1024, Wtd, (long)4096 * 640, 1);
    k_w2bf<<<8192, 256, 0, stream>>>(lg_wi, 3072, lg_wh, 1024, Wlg, (long)4096 * 512, 1);
    k_w2bf<<<4096, 256, 0, stream>>>(ar_wi, 1024, ar_wh, 1024, Wcomb, (long)4096 * 256, 1);
    k_w2bf<<<1024, 256, 0, stream>>>(ad_w, 1024, nullptr, 1024,
                                     Wcomb + (size_t)4096 * 2048, (long)1024 * 256, 0);
    k_w2bf<<<5000, 256, 0, stream>>>(out_w, 1024, nullptr, 0, Wout, (long)V * 128, 0);
    k_w2bf<<<512, 256, 0, stream>>>(arl_w, 1024, nullptr, 0, Warl, (long)1024 * 128, 0);
    k_w2bf<<<1024, 256, 0, stream>>>(af_w, 2048, nullptr, 0, Waf, (long)1024 * 256, 0);
    k_biasint<<<16, 256, 0, stream>>>(td_bi, td_bh, nullptr, bias_td, 4096);
    k_biasint<<<16, 256, 0, stream>>>(lg_bi, lg_bh, nullptr, bias_lg, 4096);
    k_biasint<<<20, 256, 0, stream>>>(ar_bi, ar_bh, ad_b, bias_comb, 5120);
    // img_att = feats_bf @ Waf^T + af_b   [4608 x 1024]
    k_gemm<<<dim3(32, 36), 256, 0, stream>>>(
        feats_bf, 2048, Waf, 2048, af_b,
        img_att, 1024, 1024, 0, nullptr, nullptr, nullptr);
    k_embslot<<<64, 256, 0, stream>>>(embs_bf, xtd, 0);   // emb slot for t=0

    // ---- timestep loop (4 dispatches each) ----
    for (int t = 0; t < TD; ++t) {
        const int* actp = active + t;
        // top-down LSTM: gates GEMM + fused pointwise
        k_gemm_lstm<<<dim3(128), 256, 0, stream>>>(
            xtd, 5120, Wtd, 5120, bias_td, 4096, 4096,
            h1, c1, actp,
            (t > 0) ? prevh_all + (size_t)(t - 1) * BD : nullptr,
            xtd + 4096, 5120, xlg + 2048, 4096, xar, 2048,
            nullptr, nullptr, nullptr, 0);
        // combined ARNet gates (fused lstm) + attention projection (h1a store)
        k_gemm_lstm<<<dim3(160), 256, 0, stream>>>(
            xar, 2048, Wcomb, 2048, bias_comb, 4096, 5120,
            arh, arc, actp, nullptr,
            xar + 1024, 2048,
            (t > 0) ? Arout + (size_t)(t - 1) * BD : (unsigned short*)nullptr, 1024,
            nullptr, 0,
            h1a, nullptr, nullptr, 0);
        k_attn<<<B, 256, 0, stream>>>(h1a, 1024, img_att, aw_w, aw_b,
                                      feats_bf, xlg);
        // language LSTM: gates GEMM + fused pointwise + h2 history + emb prefetch
        k_gemm_lstm<<<dim3(128), 256, 0, stream>>>(
            xlg, 4096, Wlg, 4096, bias_lg, 4096, 4096,
            h2, c2, actp, nullptr,
            xtd, 5120, xlg + 3072, 4096, Hout + (size_t)t * BD, 1024,
            nullptr,
            (t + 1 < TD) ? embs_bf : (const unsigned short*)nullptr, xtd, t + 1);
    }

    // ---- deferred batched GEMMs ----
    // ARNet loss over t=1..18: (Arout @ Warl^T + arl_b - prevh_all)^2 masked
    k_gemm<<<dim3(32, TD - 1), 256, 0, stream>>>(
        Arout, 1024, Warl, 1024, arl_b,
        nullptr, 0, 1024, 1, prevh_all, active + 1, loss_ptr);
    // preds for all timesteps: [19*128 x 1024] @ Wout^T -> out[b][t][v]
    // grid (313 panels, 19 t): panel-fast order -> shared A t-tile in L2
    k_gemm<<<dim3((V + 31) / 32, TD), 256, 0, stream>>>(
        Hout, 1024, Wout, 1024, out_b,
        out, 0, V, 3, nullptr, active, nullptr);
}

// Round 6
// 3227.476 us; speedup vs baseline: 1.5849x; 1.5849x over previous
//
#include <hip/hip_runtime.h>
#include <math.h>

#define B    128
#define T    20
#define TD   19      // Tdec
#define V    10000
#define D    1024
#define E    1024
#define A_DIM 1024
#define F    2048
#define NR   36
#define BD   (B * D)  // 131072

typedef __attribute__((ext_vector_type(8))) short bf16x8;
typedef __attribute__((ext_vector_type(4))) float f32x4;

__device__ __forceinline__ float sigm(float x) { return 1.f / (1.f + __expf(-x)); }

__device__ __forceinline__ unsigned short f2bf(float f) {
    union { float f; unsigned u; } x; x.f = f;
    unsigned r = x.u + 0x7fffu + ((x.u >> 16) & 1u);
    return (unsigned short)(r >> 16);
}
__device__ __forceinline__ float bf2f(unsigned short u) {
    union { float f; unsigned u; } x; x.u = ((unsigned)u) << 16; return x.f;
}
__device__ __forceinline__ uint4 pack8(const float* __restrict__ src) {
    float4 a = *(const float4*)src, b = *(const float4*)(src + 4);
    union { unsigned short u[8]; uint4 v; } p;
    p.u[0] = f2bf(a.x); p.u[1] = f2bf(a.y); p.u[2] = f2bf(a.z); p.u[3] = f2bf(a.w);
    p.u[4] = f2bf(b.x); p.u[5] = f2bf(b.y); p.u[6] = f2bf(b.z); p.u[7] = f2bf(b.w);
    return p.v;
}

// ---------------------------------------------------------------------------
// Sort (stable descending by sizes), seqs/order outputs, active counts
// ---------------------------------------------------------------------------
__global__ void k_sort_init(const int* __restrict__ sizes,
                            const int* __restrict__ sequences,
                            int* __restrict__ order,
                            int* __restrict__ active,
                            int* __restrict__ seqs_s,
                            float* __restrict__ out)
{
    int tid = threadIdx.x;                // 128 threads
    __shared__ int s_sizes[B];
    __shared__ int s_dl[B];
    s_sizes[tid] = sizes[tid];
    __syncthreads();
    int si = s_sizes[tid];
    int rank = 0;
    for (int j = 0; j < B; ++j) {
        int sj = s_sizes[j];
        if (sj > si || (sj == si && j < tid)) rank++;
    }
    order[rank] = tid;
    __syncthreads();
    int ob = order[tid];
    int dl = s_sizes[ob] - 1;
    s_dl[tid] = dl;
    for (int tt = 0; tt < T; ++tt) {
        int sq = sequences[ob * T + tt];
        seqs_s[tid * T + tt] = sq;
        out[(size_t)B * TD * V + tid * T + tt] = (float)sq;
    }
    out[(size_t)B * TD * V + B * T + tid] = (float)ob;
    __syncthreads();
    if (tid < TD) {
        int c = 0;
        for (int b = 0; b < B; ++b) c += (s_dl[b] > tid) ? 1 : 0;
        active[tid] = c;
    }
    if (tid == 0) out[(size_t)B * TD * V + B * T + B] = 0.f;   // loss accumulator
}

__global__ void k_zero(float* __restrict__ p, int n) {
    int i = blockIdx.x * 256 + threadIdx.x;
    if (i < n) p[i] = 0.f;
}

// weight f32 -> bf16, rows concatenated [s1 row (K1) | s2 row (K2)]
// s2 == nullptr with K2 > 0: zero-pad the K2 region.
// il == 1: gate-interleave row permutation: src row = (r&3)*1024 + (r>>2)
__global__ void k_w2bf(const float* __restrict__ s1, int K1,
                       const float* __restrict__ s2, int K2,
                       unsigned short* __restrict__ dst, long total /*granules*/,
                       int il)
{
    long g = (long)blockIdx.x * 256 + threadIdx.x;
    if (g >= total) return;
    int Kt = K1 + K2;
    int gpr = Kt >> 3;
    int row = (int)(g / gpr);
    int k8 = (int)(g % gpr) << 3;
    if (k8 >= K1 && !s2) {
        uint4 z{};
        *(uint4*)(dst + ((size_t)g << 3)) = z;
        return;
    }
    int srow = il ? ((row & 3) * 1024 + (row >> 2)) : row;
    const float* src = (k8 < K1) ? (s1 + (size_t)srow * K1 + k8)
                                 : (s2 + (size_t)srow * K2 + (k8 - K1));
    *(uint4*)(dst + ((size_t)g << 3)) = pack8(src);
}

// feats (sorted by order) -> bf16 [4608 x 2048]
__global__ void k_feats2bf(const float* __restrict__ feats, const int* __restrict__ order,
                           unsigned short* __restrict__ dst)
{
    long g = (long)blockIdx.x * 256 + threadIdx.x;   // 4608*256 granules
    int row = (int)(g >> 8);
    int k8 = ((int)g & 255) << 3;
    int b = row / NR, r = row - b * NR;
    const float* src = feats + ((size_t)order[b] * NR + r) * F + k8;
    *(uint4*)(dst + (size_t)row * F + k8) = pack8(src);
}

// featsAvg -> bf16 directly into xtd slot [1024,3072)
__global__ void k_favg(const float* __restrict__ feats, const int* __restrict__ order,
                       unsigned short* __restrict__ xtd)
{
    int idx = blockIdx.x * 256 + threadIdx.x;   // B*F = 262144
    int b = idx >> 11, f = idx & 2047;
    const float* base = feats + (size_t)order[b] * NR * F + f;
    float s = 0.f;
#pragma unroll
    for (int r = 0; r < NR; ++r) s += base[(size_t)r * F];
    xtd[(size_t)b * 5120 + 1024 + f] = f2bf(s * (1.f / NR));
}

// embeddings (sorted) -> bf16 [B x TD x 1024]
__global__ void k_emb2bf(const float* __restrict__ emb, const int* __restrict__ seqs_s,
                         unsigned short* __restrict__ embs_bf)
{
    long g = (long)blockIdx.x * 256 + threadIdx.x;  // B*TD*128 granules
    if (g >= (long)B * TD * 128) return;
    int b = (int)(g / (TD * 128));
    int rem = (int)(g - (long)b * (TD * 128));
    int t = rem >> 7, e8 = (rem & 127) << 3;
    const float* src = emb + (size_t)seqs_s[b * T + t] * E + e8;
    *(uint4*)(embs_bf + (((size_t)(b * TD + t)) << 10) + e8) = pack8(src);
}

// copy embs_bf[:,t,:] into xtd emb slot [3072,4096)  (used once, t=0)
__global__ void k_embslot(const unsigned short* __restrict__ embs_bf,
                          unsigned short* __restrict__ xtd, int t)
{
    int g = blockIdx.x * 256 + threadIdx.x;  // B*128 = 16384
    int b = g >> 7, e8 = (g & 127) << 3;
    *(uint4*)(xtd + (size_t)b * 5120 + 3072 + e8) =
        *(const uint4*)(embs_bf + (((size_t)(b * TD + t)) << 10) + e8);
}

// interleaved combined bias: dst[j*4+g] = bi[g*1024+j] + bh[g*1024+j]
// i >= 4096 (if n > 4096): dst[i] = extra[i-4096]
__global__ void k_biasint(const float* __restrict__ bi, const float* __restrict__ bh,
                          const float* __restrict__ extra, float* __restrict__ dst, int n)
{
    int i = blockIdx.x * 256 + threadIdx.x;
    if (i >= n) return;
    if (i < 4096) {
        int j = i >> 2, g = i & 3;
        dst[i] = bi[g * 1024 + j] + bh[g * 1024 + j];
    } else {
        dst[i] = extra[i - 4096];
    }
}

// ---------------------------------------------------------------------------
// Shared GEMM core (round-4 structure, best measured): C[m][n] = sum over Ksub
// of A[m][k]*W[n][k], tile M=128 x N=32, BK=64, 256 threads (4 waves).
// Register-staged double-buffer with statically-named register sets (rule #20),
// main loop unrolled x2 (ntile even for all Ksub used: 20/16/32).
//   global_load_dwordx4 -> named VGPR set -> ds_write -> barrier -> MFMA.
// ldw = W row stride (elements); Ksub = this block's K extent.
// smem: 2 buffers x (A 8192 ushort | W 2048 ushort) = 40960 B.
// ---------------------------------------------------------------------------
__device__ __forceinline__ void gemm_core(
    const unsigned short* __restrict__ A, int lda,
    const unsigned short* __restrict__ W, int ldw, int Ksub, int N,
    unsigned short* __restrict__ smem,
    int bm, int bn, f32x4 (&acc)[2][2])
{
    int tid = threadIdx.x, l = tid & 63, w = tid >> 6;
    int rsel = l & 15, ksel = (l >> 4) * 8;

    const unsigned short* ap[4];
#pragma unroll
    for (int i = 0; i < 4; ++i) {
        int s = 4 * w + i, mt = s >> 1, subk = s & 1;
        ap[i] = A + (size_t)(bm + mt * 16 + rsel) * lda + subk * 32 + ksel;
    }
    int nt_w = w >> 1, wsub = w & 1;
    int nr = bn + nt_w * 16 + rsel; if (nr >= N) nr = N - 1;
    const unsigned short* wp = W + (size_t)nr * ldw + wsub * 32 + ksel;
    int ntile = Ksub >> 6;     // EVEN for all Ksub used here

    uint4 rA0_0, rA0_1, rA0_2, rA0_3, rW0;   // set 0 (even tiles)
    uint4 rA1_0, rA1_1, rA1_2, rA1_3, rW1;   // set 1 (odd tiles)

    auto load0 = [&]() {
        rA0_0 = *(const uint4*)ap[0]; ap[0] += 64;
        rA0_1 = *(const uint4*)ap[1]; ap[1] += 64;
        rA0_2 = *(const uint4*)ap[2]; ap[2] += 64;
        rA0_3 = *(const uint4*)ap[3]; ap[3] += 64;
        rW0 = *(const uint4*)wp; wp += 64;
    };
    auto load1 = [&]() {
        rA1_0 = *(const uint4*)ap[0]; ap[0] += 64;
        rA1_1 = *(const uint4*)ap[1]; ap[1] += 64;
        rA1_2 = *(const uint4*)ap[2]; ap[2] += 64;
        rA1_3 = *(const uint4*)ap[3]; ap[3] += 64;
        rW1 = *(const uint4*)wp; wp += 64;
    };
    auto stash0 = [&]() {
        unsigned short* As = smem;
        *(uint4*)(As + (4 * w + 0) * 512 + l * 8) = rA0_0;
        *(uint4*)(As + (4 * w + 1) * 512 + l * 8) = rA0_1;
        *(uint4*)(As + (4 * w + 2) * 512 + l * 8) = rA0_2;
        *(uint4*)(As + (4 * w + 3) * 512 + l * 8) = rA0_3;
        *(uint4*)(As + 8192 + w * 512 + l * 8) = rW0;
    };
    auto stash1 = [&]() {
        unsigned short* As = smem + 10240;
        *(uint4*)(As + (4 * w + 0) * 512 + l * 8) = rA1_0;
        *(uint4*)(As + (4 * w + 1) * 512 + l * 8) = rA1_1;
        *(uint4*)(As + (4 * w + 2) * 512 + l * 8) = rA1_2;
        *(uint4*)(As + (4 * w + 3) * 512 + l * 8) = rA1_3;
        *(uint4*)(As + 8192 + w * 512 + l * 8) = rW1;
    };
    auto compute = [&](int p) {
        unsigned short* As = smem + p * 10240;
        unsigned short* Ws = As + 8192;
#pragma unroll
        for (int subk = 0; subk < 2; ++subk) {
            bf16x8 a0 = *(const bf16x8*)(As + (4 * w + subk) * 512 + l * 8);
            bf16x8 a1 = *(const bf16x8*)(As + (4 * w + 2 + subk) * 512 + l * 8);
            bf16x8 b0 = *(const bf16x8*)(Ws + subk * 512 + l * 8);
            bf16x8 b1 = *(const bf16x8*)(Ws + (2 + subk) * 512 + l * 8);
            acc[0][0] = __builtin_amdgcn_mfma_f32_16x16x32_bf16(a0, b0, acc[0][0], 0, 0, 0);
            acc[0][1] = __builtin_amdgcn_mfma_f32_16x16x32_bf16(a0, b1, acc[0][1], 0, 0, 0);
            acc[1][0] = __builtin_amdgcn_mfma_f32_16x16x32_bf16(a1, b0, acc[1][0], 0, 0, 0);
            acc[1][1] = __builtin_amdgcn_mfma_f32_16x16x32_bf16(a1, b1, acc[1][1], 0, 0, 0);
        }
    };

    load0(); load1();                 // tiles 0, 1 in flight
    for (int t = 0; t < ntile; t += 2) {
        // even tile t -> buffer 0
        stash0();                     // waits (counted vmcnt) on set-0 regs only
        if (t + 2 < ntile) load0();   // prefetch tile t+2
        asm volatile("s_waitcnt lgkmcnt(0)" ::: "memory");
        __builtin_amdgcn_s_barrier();
        compute(0);
        __builtin_amdgcn_s_barrier();
        // odd tile t+1 -> buffer 1
        stash1();
        if (t + 3 < ntile) load1();   // prefetch tile t+3
        asm volatile("s_waitcnt lgkmcnt(0)" ::: "memory");
        __builtin_amdgcn_s_barrier();
        compute(1);
        __builtin_amdgcn_s_barrier();
    }
}

// ---------------------------------------------------------------------------
// MFMA GEMM (modes 0 / 1 / 3 / 4)
//   0: store C = acc + bias
//   1: batched ARNet loss (no store): per blockIdx.y (= t-1), act=actp[y];
//      sum (acc+bias-sub)^2 over (row&127)<act -> atomicAdd(lossp,*0.005/act)
//   3: batched pred store, grid (nPanels, TD): panel-fast launch order means
//      concurrent blocks share one A t-tile (L2-resident) and stream W;
//      row=t*128+b -> out[b][t][col], zero if b>=actp[t]
//   4: split-K partial store: blockIdx.y = K-split index s; A,W advanced by
//      s*Ksub; store raw acc (no bias) to C + s*128*ldc. M fixed at 128.
// ---------------------------------------------------------------------------
__global__ __launch_bounds__(256)
void k_gemm(const unsigned short* __restrict__ A, int lda,
            const unsigned short* __restrict__ W, int ldw, int Ksub,
            const float* __restrict__ bias,
            float* __restrict__ C, int ldc, int N,
            int mode, const float* __restrict__ sub, const int* __restrict__ actp,
            float* __restrict__ lossp)
{
    __shared__ __align__(16) unsigned short smem[2 * 10240];   // 40 KB
    __shared__ float ps[4];

    int bn = blockIdx.x * 32, bm;
    const unsigned short* Ab = A;
    const unsigned short* Wb = W;
    float* Cb = C;
    if (mode == 4) {
        bm = 0;
        Ab += (size_t)blockIdx.y * Ksub;
        Wb += (size_t)blockIdx.y * Ksub;
        Cb  = C + (size_t)blockIdx.y * 128 * ldc;
    } else {
        bm = blockIdx.y * 128;
    }
    int tid = threadIdx.x, l = tid & 63, w = tid >> 6;

    f32x4 acc[2][2] = {};
    gemm_core(Ab, lda, Wb, ldw, Ksub, N, smem, bm, bn, acc);

    int rg4 = (l >> 4) * 4, cc = l & 15;
    if (mode == 1) {
        int act = actp[blockIdx.y];
        float s = 0.f;
#pragma unroll
        for (int mi = 0; mi < 2; ++mi) {
            int mt = 2 * w + mi;
#pragma unroll
            for (int ni = 0; ni < 2; ++ni) {
                int col = bn + ni * 16 + cc;
                float bb = bias[col];
#pragma unroll
                for (int rg = 0; rg < 4; ++rg) {
                    int row = bm + mt * 16 + rg4 + rg;
                    float v = acc[mi][ni][rg] + bb - sub[(size_t)row * 1024 + col];
                    if ((row & 127) < act) s += v * v;
                }
            }
        }
        for (int o = 32; o > 0; o >>= 1) s += __shfl_down(s, o, 64);
        if (l == 0) ps[w] = s;
        __syncthreads();
        if (tid == 0) {
            float tot = ps[0] + ps[1] + ps[2] + ps[3];
            atomicAdd(lossp, tot * (0.005f / (float)act));
        }
        return;
    }

    if (mode == 3) {
#pragma unroll
        for (int mi = 0; mi < 2; ++mi) {
            int mt = 2 * w + mi;
#pragma unroll
            for (int ni = 0; ni < 2; ++ni) {
                int col = bn + ni * 16 + cc;
                if (col >= N) continue;
                float bb = bias[col];
#pragma unroll
                for (int rg = 0; rg < 4; ++rg) {
                    int row = bm + mt * 16 + rg4 + rg;
                    int tt = row >> 7, b = row & 127;
                    float v = acc[mi][ni][rg] + bb;
                    if (b >= actp[tt]) v = 0.f;
                    C[(size_t)b * ((size_t)TD * V) + (size_t)tt * V + col] = v;
                }
            }
        }
        return;
    }

    if (mode == 4) {
#pragma unroll
        for (int mi = 0; mi < 2; ++mi) {
            int mt = 2 * w + mi;
#pragma unroll
            for (int ni = 0; ni < 2; ++ni) {
                int col = bn + ni * 16 + cc;
#pragma unroll
                for (int rg = 0; rg < 4; ++rg) {
                    int row = mt * 16 + rg4 + rg;
                    Cb[(size_t)row * ldc + col] = acc[mi][ni][rg];
                }
            }
        }
        return;
    }

#pragma unroll
    for (int mi = 0; mi < 2; ++mi) {
        int mt = 2 * w + mi;
#pragma unroll
        for (int ni = 0; ni < 2; ++ni) {
            int col = bn + ni * 16 + cc;
            if (col >= N) continue;
            float bb = bias[col];
#pragma unroll
            for (int rg = 0; rg < 4; ++rg) {
                int row = bm + mt * 16 + rg4 + rg;
                C[(size_t)row * ldc + col] = acc[mi][ni][rg] + bb;
            }
        }
    }
}

// ---------------------------------------------------------------------------
// LSTM pointwise over split-K partials: g = (sum of ns partials) + biasI.
// Partials p[s] at p + s*128*ldp, gates interleaved (unit j -> cols 4j..4j+3).
// Optional prevh capture; bf16 h into up to 3 slots; optional emb prefetch.
// ---------------------------------------------------------------------------
__global__ void k_lstm4(const float* __restrict__ p, int ldp, int ns,
                        const float* __restrict__ biasI,
                        float* __restrict__ h, float* __restrict__ c,
                        const int* __restrict__ actp, float* __restrict__ prevh,
                        unsigned short* __restrict__ s1, int ld1,
                        unsigned short* __restrict__ s2, int ld2,
                        unsigned short* __restrict__ s3, int ld3,
                        const unsigned short* __restrict__ embs_bf,
                        unsigned short* __restrict__ xtd_emb, int tnext)
{
    int idx = blockIdx.x * 256 + threadIdx.x;   // 131072
    if (embs_bf && idx < B * 128) {             // all rows, before act check
        int be = idx >> 7, e8 = (idx & 127) << 3;
        *(uint4*)(xtd_emb + (size_t)be * 5120 + 3072 + e8) =
            *(const uint4*)(embs_bf + (((size_t)(be * TD + tnext)) << 10) + e8);
    }
    int b = idx >> 10;
    if (b >= *actp) return;                     // frozen rows keep state + slots
    int j = idx & 1023;
    const float* pb = p + (size_t)b * ldp + (j << 2);
    size_t spl = (size_t)128 * ldp;
    float4 g = *(const float4*)pb;
    for (int s = 1; s < ns; ++s) {
        float4 gs = *(const float4*)(pb + (size_t)s * spl);
        g.x += gs.x; g.y += gs.y; g.z += gs.z; g.w += gs.w;
    }
    float4 bb = *(const float4*)(biasI + (j << 2));
    float gi = g.x + bb.x, gf = g.y + bb.y, gg = g.z + bb.z, go = g.w + bb.w;
    size_t ix = (size_t)b * 1024 + j;
    if (prevh) prevh[ix] = h[ix];
    float c2v = sigm(gf) * c[ix] + sigm(gi) * tanhf(gg);
    c[ix] = c2v;
    float hv = sigm(go) * tanhf(c2v);
    h[ix] = hv;
    unsigned short hb = f2bf(hv);
    if (s1) s1[(size_t)b * ld1 + j] = hb;
    if (s2) s2[(size_t)b * ld2 + j] = hb;
    if (s3) s3[(size_t)b * ld3 + j] = hb;
}

// ---------------------------------------------------------------------------
// Fused attention + ARNet LSTM, consuming comb partials (2 splits, ldp=5120):
//   h1a[a]  = pc0[b][4096+a] + pc1[b][4096+a] + bias_comb[4096+a]
//   arnet gates (interleaved cols [0,4096)) -> arh/arc update (b<act only)
//   e = relu(h1a + img_att).aw_w + aw_b ; softmax over 36 ;
//   awe = alpha^T feats_bf -> bf16 into xlg slot [0,2048)
// ---------------------------------------------------------------------------
__global__ __launch_bounds__(256)
void k_attn_ar(const float* __restrict__ pc, const float* __restrict__ bias_comb,
               const float* __restrict__ img_att,
               const float* __restrict__ aw_w, const float* __restrict__ aw_b,
               const unsigned short* __restrict__ feats_bf,
               unsigned short* __restrict__ xlg,
               float* __restrict__ arh, float* __restrict__ arc,
               const int* __restrict__ actp,
               unsigned short* __restrict__ xar_slot,   // xar+1024, ld 2048
               unsigned short* __restrict__ Arout_t)    // nullable, ld 1024
{
    int b = blockIdx.x;
    int tid = threadIdx.x;
    __shared__ float sh[A_DIM];
    __shared__ float se[NR];
    const float* p0 = pc + (size_t)b * 5120;
    const float* p1 = pc + (size_t)128 * 5120 + (size_t)b * 5120;
    for (int a = tid; a < A_DIM; a += 256)
        sh[a] = p0[4096 + a] + p1[4096 + a] + bias_comb[4096 + a];

    // ARNet LSTM for row b (independent of sh)
    int act = *actp;
    if (b < act) {
#pragma unroll
        for (int u = 0; u < 4; ++u) {
            int j = (tid << 2) + u;              // 256 threads x 4 units = 1024
            float4 ga = *(const float4*)(p0 + (j << 2));
            float4 gb = *(const float4*)(p1 + (j << 2));
            float4 bb = *(const float4*)(bias_comb + (j << 2));
            float gi = ga.x + gb.x + bb.x, gf = ga.y + gb.y + bb.y;
            float gg = ga.z + gb.z + bb.z, go = ga.w + gb.w + bb.w;
            size_t ix = (size_t)b * 1024 + j;
            float c2v = sigm(gf) * arc[ix] + sigm(gi) * tanhf(gg);
            arc[ix] = c2v;
            float hv = sigm(go) * tanhf(c2v);
            arh[ix] = hv;
            unsigned short hb = f2bf(hv);
            xar_slot[(size_t)b * 2048 + j] = hb;
            if (Arout_t) Arout_t[(size_t)b * 1024 + j] = hb;
        }
    }
    __syncthreads();

    int wid = tid >> 6, lane = tid & 63;
    for (int r = wid; r < NR; r += 4) {
        const float* row = img_att + ((size_t)b * NR + r) * A_DIM;
        float s = 0.f;
        for (int a = lane; a < A_DIM; a += 64)
            s += fmaxf(sh[a] + row[a], 0.f) * aw_w[a];
        for (int off = 32; off > 0; off >>= 1) s += __shfl_down(s, off, 64);
        if (lane == 0) se[r] = s + aw_b[0];
    }
    __syncthreads();
    if (tid == 0) {
        float m = se[0];
        for (int r = 1; r < NR; ++r) m = fmaxf(m, se[r]);
        float ssum = 0.f;
        for (int r = 0; r < NR; ++r) { float ex = __expf(se[r] - m); se[r] = ex; ssum += ex; }
        float inv = 1.f / ssum;
        for (int r = 0; r < NR; ++r) se[r] *= inv;
    }
    __syncthreads();
    // awe: each thread owns 8 consecutive f (vector loads; r-order preserved)
    int f8 = tid << 3;                                   // 256*8 = 2048 = F
    const unsigned short* fb = feats_bf + (size_t)b * NR * F + f8;
    float s[8] = {};
    for (int r = 0; r < NR; ++r) {
        bf16x8 v = *(const bf16x8*)(fb + (size_t)r * F);
        float a = se[r];
#pragma unroll
        for (int q = 0; q < 8; ++q)
            s[q] += a * bf2f(((const unsigned short*)&v)[q]);
    }
    union { unsigned short u[8]; uint4 v4; } pk;
#pragma unroll
    for (int q = 0; q < 8; ++q) pk.u[q] = f2bf(s[q]);
    *(uint4*)(xlg + (size_t)b * 4096 + f8) = pk.v4;
}

// ---------------------------------------------------------------------------
extern "C" void kernel_launch(void* const* d_in, const int* in_sizes, int n_in,
                              void* d_out, int out_size, void* d_ws, size_t ws_size,
                              hipStream_t stream)
{
    const float* feats     = (const float*)d_in[0];
    const int*   sequences = (const int*)d_in[1];
    const int*   sizes     = (const int*)d_in[2];
    const float* emb       = (const float*)d_in[3];
    const float* td_wi = (const float*)d_in[4];
    const float* td_wh = (const float*)d_in[5];
    const float* td_bi = (const float*)d_in[6];
    const float* td_bh = (const float*)d_in[7];
    const float* lg_wi = (const float*)d_in[8];
    const float* lg_wh = (const float*)d_in[9];
    const float* lg_bi = (const float*)d_in[10];
    const float* lg_bh = (const float*)d_in[11];
    const float* ar_wi = (const float*)d_in[12];
    const float* ar_wh = (const float*)d_in[13];
    const float* ar_bi = (const float*)d_in[14];
    const float* ar_bh = (const float*)d_in[15];
    const float* arl_w = (const float*)d_in[16];
    const float* arl_b = (const float*)d_in[17];
    const float* out_w = (const float*)d_in[18];
    const float* out_b = (const float*)d_in[19];
    const float* af_w  = (const float*)d_in[20];
    const float* af_b  = (const float*)d_in[21];
    const float* ad_w  = (const float*)d_in[22];
    const float* ad_b  = (const float*)d_in[23];
    const float* aw_w  = (const float*)d_in[24];
    const float* aw_b  = (const float*)d_in[25];
    float* out = (float*)d_out;

    // ---- workspace carve (floats; every region multiple of 4 floats) ----
    float* ws = (float*)d_ws;
    size_t off = 0;
    auto alloc = [&](size_t n) { float* p = ws + off; off += n; return p; };
    // zero region: 6 f32 states + xtd + xlg + xar (contiguous)
    float* h1   = alloc((size_t)BD);
    float* c1   = alloc((size_t)BD);
    float* h2   = alloc((size_t)BD);
    float* c2   = alloc((size_t)BD);
    float* arh  = alloc((size_t)BD);
    float* arc  = alloc((size_t)BD);
    unsigned short* xtd = (unsigned short*)alloc((size_t)B * 5120 / 2);
    unsigned short* xlg = (unsigned short*)alloc((size_t)B * 4096 / 2);
    unsigned short* xar = (unsigned short*)alloc((size_t)B * 2048 / 2);
    int zero_n = 6 * BD + (B * 5120 + B * 4096 + B * 2048) / 2;  // 1,507,328
    // rest
    float* gpart     = alloc((size_t)4 * 128 * 5120);    // split-K partials
    float* prevh_all = alloc((size_t)(TD - 1) * BD);     // f32 h1 history (t=1..18)
    float* img_att   = alloc((size_t)B * NR * A_DIM);
    float* bias_td   = alloc(4096);
    float* bias_lg   = alloc(4096);
    float* bias_comb = alloc(5120);
    unsigned short* embs_bf  = (unsigned short*)alloc((size_t)B * TD * E / 2);
    unsigned short* feats_bf = (unsigned short*)alloc((size_t)B * NR * F / 2);
    unsigned short* Hout     = (unsigned short*)alloc((size_t)TD * BD / 2);       // h2 history
    unsigned short* Arout    = (unsigned short*)alloc((size_t)(TD - 1) * BD / 2); // arh history
    unsigned short* Wtd  = (unsigned short*)alloc((size_t)4096 * 5120 / 2);
    unsigned short* Wlg  = (unsigned short*)alloc((size_t)4096 * 4096 / 2);
    unsigned short* Wcomb = (unsigned short*)alloc((size_t)5120 * 2048 / 2);  // [War-il | Wad-pad]
    unsigned short* Wout = (unsigned short*)alloc((size_t)10048 * 1024 / 2); // V padded to panel
    unsigned short* Warl = (unsigned short*)alloc((size_t)1024 * 1024 / 2);
    unsigned short* Waf  = (unsigned short*)alloc((size_t)1024 * 2048 / 2);
    int* ip     = (int*)(ws + off);
    int* order  = ip; ip += B;
    int* active = ip; ip += TD + 1;
    int* seqs_s = ip; ip += B * T;

    float* loss_ptr = out + (size_t)B * TD * V + B * T + B;

    // ---- prologue ----
    k_sort_init<<<1, B, 0, stream>>>(sizes, sequences, order, active, seqs_s, out);
    k_zero<<<(zero_n + 255) / 256, 256, 0, stream>>>(h1, zero_n);
    k_favg<<<1024, 256, 0, stream>>>(feats, order, xtd);
    k_emb2bf<<<(B * TD * 128 + 255) / 256, 256, 0, stream>>>(emb, seqs_s, embs_bf);
    k_feats2bf<<<4608, 256, 0, stream>>>(feats, order, feats_bf);
    k_w2bf<<<10240, 256, 0, stream>>>(td_wi, 4096, td_wh, 1024, Wtd, (long)4096 * 640, 1);
    k_w2bf<<<8192, 256, 0, stream>>>(lg_wi, 3072, lg_wh, 1024, Wlg, (long)4096 * 512, 1);
    k_w2bf<<<4096, 256, 0, stream>>>(ar_wi, 1024, ar_wh, 1024, Wcomb, (long)4096 * 256, 1);
    k_w2bf<<<1024, 256, 0, stream>>>(ad_w, 1024, nullptr, 1024,
                                     Wcomb + (size_t)4096 * 2048, (long)1024 * 256, 0);
    k_w2bf<<<5000, 256, 0, stream>>>(out_w, 1024, nullptr, 0, Wout, (long)V * 128, 0);
    k_w2bf<<<512, 256, 0, stream>>>(arl_w, 1024, nullptr, 0, Warl, (long)1024 * 128, 0);
    k_w2bf<<<1024, 256, 0, stream>>>(af_w, 2048, nullptr, 0, Waf, (long)1024 * 256, 0);
    k_biasint<<<16, 256, 0, stream>>>(td_bi, td_bh, nullptr, bias_td, 4096);
    k_biasint<<<16, 256, 0, stream>>>(lg_bi, lg_bh, nullptr, bias_lg, 4096);
    k_biasint<<<20, 256, 0, stream>>>(ar_bi, ar_bh, ad_b, bias_comb, 5120);
    // img_att = feats_bf @ Waf^T + af_b   [4608 x 1024]
    k_gemm<<<dim3(32, 36), 256, 0, stream>>>(
        feats_bf, 2048, Waf, 2048, 2048, af_b,
        img_att, 1024, 1024, 0, nullptr, nullptr, nullptr);
    k_embslot<<<64, 256, 0, stream>>>(embs_bf, xtd, 0);   // emb slot for t=0

    // ---- timestep loop (6 dispatches each) ----
    for (int t = 0; t < TD; ++t) {
        const int* actp = active + t;
        // top-down LSTM gates: split-K=4 (Ksub=1280) -> partials
        k_gemm<<<dim3(128, 4), 256, 0, stream>>>(
            xtd, 5120, Wtd, 5120, 1280, nullptr,
            gpart, 4096, 4096, 4, nullptr, nullptr, nullptr);
        k_lstm4<<<512, 256, 0, stream>>>(gpart, 4096, 4, bias_td,
            h1, c1, actp,
            (t > 0) ? prevh_all + (size_t)(t - 1) * BD : nullptr,
            xtd + 4096, 5120, xlg + 2048, 4096, xar, 2048,
            nullptr, nullptr, 0);
        // combined ARNet gates + attention projection: split-K=2 (Ksub=1024)
        k_gemm<<<dim3(160, 2), 256, 0, stream>>>(
            xar, 2048, Wcomb, 2048, 1024, nullptr,
            gpart, 5120, 5120, 4, nullptr, nullptr, nullptr);
        // fused: h1a sum + attention + ARNet LSTM update
        k_attn_ar<<<B, 256, 0, stream>>>(
            gpart, bias_comb, img_att, aw_w, aw_b, feats_bf, xlg,
            arh, arc, actp, xar + 1024,
            (t > 0) ? Arout + (size_t)(t - 1) * BD : (unsigned short*)nullptr);
        // language LSTM gates: split-K=4 (Ksub=1024) -> partials
        k_gemm<<<dim3(128, 4), 256, 0, stream>>>(
            xlg, 4096, Wlg, 4096, 1024, nullptr,
            gpart, 4096, 4096, 4, nullptr, nullptr, nullptr);
        k_lstm4<<<512, 256, 0, stream>>>(gpart, 4096, 4, bias_lg,
            h2, c2, actp, nullptr,
            xtd, 5120, xlg + 3072, 4096, Hout + (size_t)t * BD, 1024,
            (t + 1 < TD) ? embs_bf : (const unsigned short*)nullptr, xtd, t + 1);
    }

    // ---- deferred batched GEMMs ----
    // ARNet loss over t=1..18: (Arout @ Warl^T + arl_b - prevh_all)^2 masked
    k_gemm<<<dim3(32, TD - 1), 256, 0, stream>>>(
        Arout, 1024, Warl, 1024, 1024, arl_b,
        nullptr, 0, 1024, 1, prevh_all, active + 1, loss_ptr);
    // preds for all timesteps: [19*128 x 1024] @ Wout^T -> out[b][t][v]
    // grid (313 panels, 19 t): panel-fast order -> shared A t-tile in L2
    k_gemm<<<dim3((V + 31) / 32, TD), 256, 0, stream>>>(
        Hout, 1024, Wout, 1024, 1024, out_b,
        out, 0, V, 3, nullptr, active, nullptr);
}

// Round 8
// 2945.657 us; speedup vs baseline: 1.7366x; 1.0957x over previous
//
#include <hip/hip_runtime.h>
#include <math.h>

#define B    128
#define T    20
#define TD   19      // Tdec
#define V    10000
#define D    1024
#define E    1024
#define A_DIM 1024
#define F    2048
#define NR   36
#define BD   (B * D)  // 131072

typedef __attribute__((ext_vector_type(8))) short bf16x8;
typedef __attribute__((ext_vector_type(4))) float f32x4;

__device__ __forceinline__ float sigm(float x) { return 1.f / (1.f + __expf(-x)); }

__device__ __forceinline__ unsigned short f2bf(float f) {
    union { float f; unsigned u; } x; x.f = f;
    unsigned r = x.u + 0x7fffu + ((x.u >> 16) & 1u);
    return (unsigned short)(r >> 16);
}
__device__ __forceinline__ float bf2f(unsigned short u) {
    union { float f; unsigned u; } x; x.u = ((unsigned)u) << 16; return x.f;
}
__device__ __forceinline__ uint4 pack8(const float* __restrict__ src) {
    float4 a = *(const float4*)src, b = *(const float4*)(src + 4);
    union { unsigned short u[8]; uint4 v; } p;
    p.u[0] = f2bf(a.x); p.u[1] = f2bf(a.y); p.u[2] = f2bf(a.z); p.u[3] = f2bf(a.w);
    p.u[4] = f2bf(b.x); p.u[5] = f2bf(b.y); p.u[6] = f2bf(b.z); p.u[7] = f2bf(b.w);
    return p.v;
}

// ---------------------------------------------------------------------------
// Sort (stable descending by sizes), seqs/order outputs, active counts
// ---------------------------------------------------------------------------
__global__ void k_sort_init(const int* __restrict__ sizes,
                            const int* __restrict__ sequences,
                            int* __restrict__ order,
                            int* __restrict__ active,
                            int* __restrict__ seqs_s,
                            float* __restrict__ out)
{
    int tid = threadIdx.x;                // 128 threads
    __shared__ int s_sizes[B];
    __shared__ int s_dl[B];
    s_sizes[tid] = sizes[tid];
    __syncthreads();
    int si = s_sizes[tid];
    int rank = 0;
    for (int j = 0; j < B; ++j) {
        int sj = s_sizes[j];
        if (sj > si || (sj == si && j < tid)) rank++;
    }
    order[rank] = tid;
    __syncthreads();
    int ob = order[tid];
    int dl = s_sizes[ob] - 1;
    s_dl[tid] = dl;
    for (int tt = 0; tt < T; ++tt) {
        int sq = sequences[ob * T + tt];
        seqs_s[tid * T + tt] = sq;
        out[(size_t)B * TD * V + tid * T + tt] = (float)sq;
    }
    out[(size_t)B * TD * V + B * T + tid] = (float)ob;
    __syncthreads();
    if (tid < TD) {
        int c = 0;
        for (int b = 0; b < B; ++b) c += (s_dl[b] > tid) ? 1 : 0;
        active[tid] = c;
    }
    if (tid == 0) out[(size_t)B * TD * V + B * T + B] = 0.f;   // loss accumulator
}

__global__ void k_zero(float* __restrict__ p, int n) {
    int i = blockIdx.x * 256 + threadIdx.x;
    if (i < n) p[i] = 0.f;
}

// weight f32 -> bf16, rows concatenated [s1 row (K1) | s2 row (K2)]
// s2 == nullptr with K2 > 0: zero-pad the K2 region.
// il == 1: gate-interleave row permutation: src row = (r&3)*1024 + (r>>2)
__global__ void k_w2bf(const float* __restrict__ s1, int K1,
                       const float* __restrict__ s2, int K2,
                       unsigned short* __restrict__ dst, long total /*granules*/,
                       int il)
{
    long g = (long)blockIdx.x * 256 + threadIdx.x;
    if (g >= total) return;
    int Kt = K1 + K2;
    int gpr = Kt >> 3;
    int row = (int)(g / gpr);
    int k8 = (int)(g % gpr) << 3;
    if (k8 >= K1 && !s2) {
        uint4 z{};
        *(uint4*)(dst + ((size_t)g << 3)) = z;
        return;
    }
    int srow = il ? ((row & 3) * 1024 + (row >> 2)) : row;
    const float* src = (k8 < K1) ? (s1 + (size_t)srow * K1 + k8)
                                 : (s2 + (size_t)srow * K2 + (k8 - K1));
    *(uint4*)(dst + ((size_t)g << 3)) = pack8(src);
}

// feats (sorted by order) -> bf16 [4608 x 2048]
__global__ void k_feats2bf(const float* __restrict__ feats, const int* __restrict__ order,
                           unsigned short* __restrict__ dst)
{
    long g = (long)blockIdx.x * 256 + threadIdx.x;   // 4608*256 granules
    int row = (int)(g >> 8);
    int k8 = ((int)g & 255) << 3;
    int b = row / NR, r = row - b * NR;
    const float* src = feats + ((size_t)order[b] * NR + r) * F + k8;
    *(uint4*)(dst + (size_t)row * F + k8) = pack8(src);
}

// featsAvg -> bf16 directly into xtd slot [1024,3072)
__global__ void k_favg(const float* __restrict__ feats, const int* __restrict__ order,
                       unsigned short* __restrict__ xtd)
{
    int idx = blockIdx.x * 256 + threadIdx.x;   // B*F = 262144
    int b = idx >> 11, f = idx & 2047;
    const float* base = feats + (size_t)order[b] * NR * F + f;
    float s = 0.f;
#pragma unroll
    for (int r = 0; r < NR; ++r) s += base[(size_t)r * F];
    xtd[(size_t)b * 5120 + 1024 + f] = f2bf(s * (1.f / NR));
}

// embeddings (sorted) -> bf16 [B x TD x 1024], row index m = b*TD + t
__global__ void k_emb2bf(const float* __restrict__ emb, const int* __restrict__ seqs_s,
                         unsigned short* __restrict__ embs_bf)
{
    long g = (long)blockIdx.x * 256 + threadIdx.x;  // B*TD*128 granules
    if (g >= (long)B * TD * 128) return;
    int b = (int)(g / (TD * 128));
    int rem = (int)(g - (long)b * (TD * 128));
    int t = rem >> 7, e8 = (rem & 127) << 3;
    const float* src = emb + (size_t)seqs_s[b * T + t] * E + e8;
    *(uint4*)(embs_bf + (((size_t)(b * TD + t)) << 10) + e8) = pack8(src);
}

// interleaved combined bias: dst[j*4+g] = bi[g*1024+j] + bh[g*1024+j]
// i >= 4096 (if n > 4096): dst[i] = extra[i-4096]
__global__ void k_biasint(const float* __restrict__ bi, const float* __restrict__ bh,
                          const float* __restrict__ extra, float* __restrict__ dst, int n)
{
    int i = blockIdx.x * 256 + threadIdx.x;
    if (i >= n) return;
    if (i < 4096) {
        int j = i >> 2, g = i & 3;
        dst[i] = bi[g * 1024 + j] + bh[g * 1024 + j];
    } else {
        dst[i] = extra[i - 4096];
    }
}

// ---------------------------------------------------------------------------
// Shared GEMM core (round-4 structure, best measured), templated on NT
// (number of 16-col N-tiles per block; N-width = NT*16, NT = 2 or 4).
// Tile M=128 x N=NT*16, BK=64, 256 threads (4 waves). Register-staged
// double-buffer with statically-named register sets (rule #20), loop
// unrolled x2 (ntile even for all Ksub used: 8/16/32).
// smem: 2 buffers x (A 8192 + W NT*1024 ushorts).
// ---------------------------------------------------------------------------
template<int NT>
__device__ __forceinline__ void gemm_core(
    const unsigned short* __restrict__ A, int lda,
    const unsigned short* __restrict__ W, int ldw, int Ksub, int N,
    unsigned short* __restrict__ smem,
    int bm, int bn, f32x4 (&acc)[2][NT])
{
    const int BUF = 8192 + NT * 1024;
    int tid = threadIdx.x, l = tid & 63, w = tid >> 6;
    int rsel = l & 15, ksel = (l >> 4) * 8;

    const unsigned short* ap[4];
#pragma unroll
    for (int i = 0; i < 4; ++i) {
        int s = 4 * w + i, mt = s >> 1, subk = s & 1;
        ap[i] = A + (size_t)(bm + mt * 16 + rsel) * lda + subk * 32 + ksel;
    }
    int nt_w = w >> 1, wsub = w & 1;
    int nr0 = bn + nt_w * 16 + rsel; if (nr0 >= N) nr0 = N - 1;
    const unsigned short* wp0 = W + (size_t)nr0 * ldw + wsub * 32 + ksel;
    const unsigned short* wp1 = wp0;
    if (NT == 4) {
        int nr1 = bn + 32 + nt_w * 16 + rsel; if (nr1 >= N) nr1 = N - 1;
        wp1 = W + (size_t)nr1 * ldw + wsub * 32 + ksel;
    }
    int ntile = Ksub >> 6;     // EVEN for all Ksub used here

    uint4 rA0_0, rA0_1, rA0_2, rA0_3, rW0a, rW0b;   // set 0 (even tiles)
    uint4 rA1_0, rA1_1, rA1_2, rA1_3, rW1a, rW1b;   // set 1 (odd tiles)

    auto load0 = [&]() {
        rA0_0 = *(const uint4*)ap[0]; ap[0] += 64;
        rA0_1 = *(const uint4*)ap[1]; ap[1] += 64;
        rA0_2 = *(const uint4*)ap[2]; ap[2] += 64;
        rA0_3 = *(const uint4*)ap[3]; ap[3] += 64;
        rW0a = *(const uint4*)wp0; wp0 += 64;
        if (NT == 4) { rW0b = *(const uint4*)wp1; wp1 += 64; }
    };
    auto load1 = [&]() {
        rA1_0 = *(const uint4*)ap[0]; ap[0] += 64;
        rA1_1 = *(const uint4*)ap[1]; ap[1] += 64;
        rA1_2 = *(const uint4*)ap[2]; ap[2] += 64;
        rA1_3 = *(const uint4*)ap[3]; ap[3] += 64;
        rW1a = *(const uint4*)wp0; wp0 += 64;
        if (NT == 4) { rW1b = *(const uint4*)wp1; wp1 += 64; }
    };
    auto stash0 = [&]() {
        unsigned short* As = smem;
        *(uint4*)(As + (4 * w + 0) * 512 + l * 8) = rA0_0;
        *(uint4*)(As + (4 * w + 1) * 512 + l * 8) = rA0_1;
        *(uint4*)(As + (4 * w + 2) * 512 + l * 8) = rA0_2;
        *(uint4*)(As + (4 * w + 3) * 512 + l * 8) = rA0_3;
        *(uint4*)(As + 8192 + w * 512 + l * 8) = rW0a;
        if (NT == 4) *(uint4*)(As + 8192 + (4 + w) * 512 + l * 8) = rW0b;
    };
    auto stash1 = [&]() {
        unsigned short* As = smem + BUF;
        *(uint4*)(As + (4 * w + 0) * 512 + l * 8) = rA1_0;
        *(uint4*)(As + (4 * w + 1) * 512 + l * 8) = rA1_1;
        *(uint4*)(As + (4 * w + 2) * 512 + l * 8) = rA1_2;
        *(uint4*)(As + (4 * w + 3) * 512 + l * 8) = rA1_3;
        *(uint4*)(As + 8192 + w * 512 + l * 8) = rW1a;
        if (NT == 4) *(uint4*)(As + 8192 + (4 + w) * 512 + l * 8) = rW1b;
    };
    auto compute = [&](int p) {
        unsigned short* As = smem + p * BUF;
        unsigned short* Ws = As + 8192;
#pragma unroll
        for (int subk = 0; subk < 2; ++subk) {
            bf16x8 a0 = *(const bf16x8*)(As + (4 * w + subk) * 512 + l * 8);
            bf16x8 a1 = *(const bf16x8*)(As + (4 * w + 2 + subk) * 512 + l * 8);
#pragma unroll
            for (int nt = 0; nt < NT; ++nt) {
                bf16x8 bb = *(const bf16x8*)(Ws + (nt * 2 + subk) * 512 + l * 8);
                acc[0][nt] = __builtin_amdgcn_mfma_f32_16x16x32_bf16(a0, bb, acc[0][nt], 0, 0, 0);
                acc[1][nt] = __builtin_amdgcn_mfma_f32_16x16x32_bf16(a1, bb, acc[1][nt], 0, 0, 0);
            }
        }
    };

    load0(); load1();                 // tiles 0, 1 in flight
    for (int t = 0; t < ntile; t += 2) {
        stash0();
        if (t + 2 < ntile) load0();
        asm volatile("s_waitcnt lgkmcnt(0)" ::: "memory");
        __builtin_amdgcn_s_barrier();
        compute(0);
        __builtin_amdgcn_s_barrier();
        stash1();
        if (t + 3 < ntile) load1();
        asm volatile("s_waitcnt lgkmcnt(0)" ::: "memory");
        __builtin_amdgcn_s_barrier();
        compute(1);
        __builtin_amdgcn_s_barrier();
    }
}

// ---------------------------------------------------------------------------
// MFMA GEMM (modes 0 / 1 / 3 / 4 / 6), N-width = NT*16
//   0: store C = acc (+ bias if non-null); bm = y*128
//   1: batched ARNet loss (no store): per blockIdx.y (= t-1), act=actp[y];
//      sum (acc+bias-sub)^2 over (row&127)<act -> atomicAdd(lossp,*0.005/act)
//   3: batched pred store, grid (nPanels, TD): row=t*128+b -> out[b][t][col],
//      zero if b>=actp[t]
//   4: split-K partial: y = split; A,W += y*Ksub; raw acc -> C + y*128*ldc
//   6: split-K partial with td offsets: o = (y>>1)*4096 + (y&1)*512
// ---------------------------------------------------------------------------
template<int NT>
__global__ __launch_bounds__(256)
void k_gemm(const unsigned short* __restrict__ A, int lda,
            const unsigned short* __restrict__ W, int ldw, int Ksub,
            const float* __restrict__ bias,
            float* __restrict__ C, int ldc, int N,
            int mode, const float* __restrict__ sub, const int* __restrict__ actp,
            float* __restrict__ lossp)
{
    __shared__ __align__(16) unsigned short smem[2 * (8192 + NT * 1024)];
    __shared__ float ps[4];

    int bn = blockIdx.x * (NT * 16), bm;
    const unsigned short* Ab = A;
    const unsigned short* Wb = W;
    float* Cb = C;
    if (mode == 4 || mode == 6) {
        bm = 0;
        size_t o = (mode == 4) ? (size_t)blockIdx.y * Ksub
                               : (size_t)(blockIdx.y >> 1) * 4096 + (blockIdx.y & 1) * 512;
        Ab += o; Wb += o;
        Cb  = C + (size_t)blockIdx.y * 128 * ldc;
    } else {
        bm = blockIdx.y * 128;
    }
    int tid = threadIdx.x, l = tid & 63, w = tid >> 6;

    f32x4 acc[2][NT];
#pragma unroll
    for (int mi = 0; mi < 2; ++mi)
#pragma unroll
        for (int ni = 0; ni < NT; ++ni) acc[mi][ni] = (f32x4){0.f, 0.f, 0.f, 0.f};
    gemm_core<NT>(Ab, lda, Wb, ldw, Ksub, N, smem, bm, bn, acc);

    int rg4 = (l >> 4) * 4, cc = l & 15;
    if (mode == 1) {
        int act = actp[blockIdx.y];
        float s = 0.f;
#pragma unroll
        for (int mi = 0; mi < 2; ++mi) {
            int mt = 2 * w + mi;
#pragma unroll
            for (int ni = 0; ni < NT; ++ni) {
                int col = bn + ni * 16 + cc;
                float bb = bias[col];
#pragma unroll
                for (int rg = 0; rg < 4; ++rg) {
                    int row = bm + mt * 16 + rg4 + rg;
                    float v = acc[mi][ni][rg] + bb - sub[(size_t)row * 1024 + col];
                    if ((row & 127) < act) s += v * v;
                }
            }
        }
        for (int o = 32; o > 0; o >>= 1) s += __shfl_down(s, o, 64);
        if (l == 0) ps[w] = s;
        __syncthreads();
        if (tid == 0) {
            float tot = ps[0] + ps[1] + ps[2] + ps[3];
            atomicAdd(lossp, tot * (0.005f / (float)act));
        }
        return;
    }

    if (mode == 3) {
#pragma unroll
        for (int mi = 0; mi < 2; ++mi) {
            int mt = 2 * w + mi;
#pragma unroll
            for (int ni = 0; ni < NT; ++ni) {
                int col = bn + ni * 16 + cc;
                if (col >= N) continue;
                float bb = bias[col];
#pragma unroll
                for (int rg = 0; rg < 4; ++rg) {
                    int row = bm + mt * 16 + rg4 + rg;
                    int tt = row >> 7, b = row & 127;
                    float v = acc[mi][ni][rg] + bb;
                    if (b >= actp[tt]) v = 0.f;
                    C[(size_t)b * ((size_t)TD * V) + (size_t)tt * V + col] = v;
                }
            }
        }
        return;
    }

    if (mode == 4 || mode == 6) {
#pragma unroll
        for (int mi = 0; mi < 2; ++mi) {
            int mt = 2 * w + mi;
#pragma unroll
            for (int ni = 0; ni < NT; ++ni) {
                int col = bn + ni * 16 + cc;
#pragma unroll
                for (int rg = 0; rg < 4; ++rg) {
                    int row = mt * 16 + rg4 + rg;
                    Cb[(size_t)row * ldc + col] = acc[mi][ni][rg];
                }
            }
        }
        return;
    }

#pragma unroll
    for (int mi = 0; mi < 2; ++mi) {
        int mt = 2 * w + mi;
#pragma unroll
        for (int ni = 0; ni < NT; ++ni) {
            int col = bn + ni * 16 + cc;
            if (col >= N) continue;
            float bb = bias ? bias[col] : 0.f;
#pragma unroll
            for (int rg = 0; rg < 4; ++rg) {
                int row = bm + mt * 16 + rg4 + rg;
                C[(size_t)row * ldc + col] = acc[mi][ni][rg] + bb;
            }
        }
    }
}

// ---------------------------------------------------------------------------
// LSTM pointwise over split-K partials: g = sum(ns partials) (+e1) (+e2) + bias.
// Partials p[s] at p + s*128*ldp, gates interleaved (unit j -> cols 4j..4j+3).
// e1: per-b extra (ld 4096), e2: per-b extra with row stride e2ldb (both nullable).
// ---------------------------------------------------------------------------
__global__ void k_lstm4(const float* __restrict__ p, int ldp, int ns,
                        const float* __restrict__ biasI,
                        const float* __restrict__ e1,
                        const float* __restrict__ e2, int e2ldb,
                        float* __restrict__ h, float* __restrict__ c,
                        const int* __restrict__ actp, float* __restrict__ prevh,
                        unsigned short* __restrict__ s1, int ld1,
                        unsigned short* __restrict__ s2, int ld2,
                        unsigned short* __restrict__ s3, int ld3)
{
    int idx = blockIdx.x * 256 + threadIdx.x;   // 131072
    int b = idx >> 10;
    if (b >= *actp) return;                     // frozen rows keep state + slots
    int j = idx & 1023;
    const float* pb = p + (size_t)b * ldp + (j << 2);
    size_t spl = (size_t)128 * ldp;
    float4 g = *(const float4*)pb;
    for (int s = 1; s < ns; ++s) {
        float4 gs = *(const float4*)(pb + (size_t)s * spl);
        g.x += gs.x; g.y += gs.y; g.z += gs.z; g.w += gs.w;
    }
    if (e1) {
        float4 ge = *(const float4*)(e1 + ((size_t)b << 12) + (j << 2));
        g.x += ge.x; g.y += ge.y; g.z += ge.z; g.w += ge.w;
    }
    if (e2) {
        float4 ge = *(const float4*)(e2 + (size_t)b * e2ldb + (j << 2));
        g.x += ge.x; g.y += ge.y; g.z += ge.z; g.w += ge.w;
    }
    float4 bb = *(const float4*)(biasI + (j << 2));
    float gi = g.x + bb.x, gf = g.y + bb.y, gg = g.z + bb.z, go = g.w + bb.w;
    size_t ix = (size_t)b * 1024 + j;
    if (prevh) prevh[ix] = h[ix];
    float c2v = sigm(gf) * c[ix] + sigm(gi) * tanhf(gg);
    c[ix] = c2v;
    float hv = sigm(go) * tanhf(c2v);
    h[ix] = hv;
    unsigned short hb = f2bf(hv);
    if (s1) s1[(size_t)b * ld1 + j] = hb;
    if (s2) s2[(size_t)b * ld2 + j] = hb;
    if (s3) s3[(size_t)b * ld3 + j] = hb;
}

// ---------------------------------------------------------------------------
// Fused attention + ARNet LSTM, consuming comb partials (4 splits, ldp=5120):
//   h1a[a]  = sum_s pc_s[b][4096+a] + bias_comb[4096+a]
//   arnet gates (interleaved cols [0,4096)) -> arh/arc update (b<act only)
//   e = relu(h1a + img_att).aw_w + aw_b ; softmax over 36 ;
//   awe = alpha^T feats_bf -> bf16 into xlg slot [0,2048)
// ---------------------------------------------------------------------------
__global__ __launch_bounds__(256)
void k_attn_ar(const float* __restrict__ pc, const float* __restrict__ bias_comb,
               const float* __restrict__ img_att,
               const float* __restrict__ aw_w, const float* __restrict__ aw_b,
               const unsigned short* __restrict__ feats_bf,
               unsigned short* __restrict__ xlg,
               float* __restrict__ arh, float* __restrict__ arc,
               const int* __restrict__ actp,
               unsigned short* __restrict__ xar_slot,   // xar+1024, ld 2048
               unsigned short* __restrict__ Arout_t)    // nullable, ld 1024
{
    int b = blockIdx.x;
    int tid = threadIdx.x;
    __shared__ float sh[A_DIM];
    __shared__ float se[NR];
    const float* pb = pc + (size_t)b * 5120;
    const size_t spl = (size_t)128 * 5120;
    for (int a = tid; a < A_DIM; a += 256) {
        float v = bias_comb[4096 + a];
#pragma unroll
        for (int s = 0; s < 4; ++s) v += pb[s * spl + 4096 + a];
        sh[a] = v;
    }

    // ARNet LSTM for row b (independent of sh)
    int act = *actp;
    if (b < act) {
#pragma unroll
        for (int u = 0; u < 4; ++u) {
            int j = (tid << 2) + u;              // 256 threads x 4 units = 1024
            float4 g = *(const float4*)(pb + (j << 2));
#pragma unroll
            for (int s = 1; s < 4; ++s) {
                float4 gs = *(const float4*)(pb + s * spl + (j << 2));
                g.x += gs.x; g.y += gs.y; g.z += gs.z; g.w += gs.w;
            }
            float4 bb = *(const float4*)(bias_comb + (j << 2));
            float gi = g.x + bb.x, gf = g.y + bb.y;
            float gg = g.z + bb.z, go = g.w + bb.w;
            size_t ix = (size_t)b * 1024 + j;
            float c2v = sigm(gf) * arc[ix] + sigm(gi) * tanhf(gg);
            arc[ix] = c2v;
            float hv = sigm(go) * tanhf(c2v);
            arh[ix] = hv;
            unsigned short hb = f2bf(hv);
            xar_slot[(size_t)b * 2048 + j] = hb;
            if (Arout_t) Arout_t[(size_t)b * 1024 + j] = hb;
        }
    }
    __syncthreads();

    int wid = tid >> 6, lane = tid & 63;
    for (int r = wid; r < NR; r += 4) {
        const float* row = img_att + ((size_t)b * NR + r) * A_DIM;
        float s = 0.f;
        for (int a = lane; a < A_DIM; a += 64)
            s += fmaxf(sh[a] + row[a], 0.f) * aw_w[a];
        for (int off = 32; off > 0; off >>= 1) s += __shfl_down(s, off, 64);
        if (lane == 0) se[r] = s + aw_b[0];
    }
    __syncthreads();
    if (tid == 0) {
        float m = se[0];
        for (int r = 1; r < NR; ++r) m = fmaxf(m, se[r]);
        float ssum = 0.f;
        for (int r = 0; r < NR; ++r) { float ex = __expf(se[r] - m); se[r] = ex; ssum += ex; }
        float inv = 1.f / ssum;
        for (int r = 0; r < NR; ++r) se[r] *= inv;
    }
    __syncthreads();
    // awe: each thread owns 8 consecutive f (vector loads; r-order preserved)
    int f8 = tid << 3;                                   // 256*8 = 2048 = F
    const unsigned short* fb = feats_bf + (size_t)b * NR * F + f8;
    float s[8] = {};
    for (int r = 0; r < NR; ++r) {
        bf16x8 v = *(const bf16x8*)(fb + (size_t)r * F);
        float a = se[r];
#pragma unroll
        for (int q = 0; q < 8; ++q)
            s[q] += a * bf2f(((const unsigned short*)&v)[q]);
    }
    union { unsigned short u[8]; uint4 v4; } pk;
#pragma unroll
    for (int q = 0; q < 8; ++q) pk.u[q] = f2bf(s[q]);
    *(uint4*)(xlg + (size_t)b * 4096 + f8) = pk.v4;
}

// ---------------------------------------------------------------------------
extern "C" void kernel_launch(void* const* d_in, const int* in_sizes, int n_in,
                              void* d_out, int out_size, void* d_ws, size_t ws_size,
                              hipStream_t stream)
{
    const float* feats     = (const float*)d_in[0];
    const int*   sequences = (const int*)d_in[1];
    const int*   sizes     = (const int*)d_in[2];
    const float* emb       = (const float*)d_in[3];
    const float* td_wi = (const float*)d_in[4];
    const float* td_wh = (const float*)d_in[5];
    const float* td_bi = (const float*)d_in[6];
    const float* td_bh = (const float*)d_in[7];
    const float* lg_wi = (const float*)d_in[8];
    const float* lg_wh = (const float*)d_in[9];
    const float* lg_bi = (const float*)d_in[10];
    const float* lg_bh = (const float*)d_in[11];
    const float* ar_wi = (const float*)d_in[12];
    const float* ar_wh = (const float*)d_in[13];
    const float* ar_bi = (const float*)d_in[14];
    const float* ar_bh = (const float*)d_in[15];
    const float* arl_w = (const float*)d_in[16];
    const float* arl_b = (const float*)d_in[17];
    const float* out_w = (const float*)d_in[18];
    const float* out_b = (const float*)d_in[19];
    const float* af_w  = (const float*)d_in[20];
    const float* af_b  = (const float*)d_in[21];
    const float* ad_w  = (const float*)d_in[22];
    const float* ad_b  = (const float*)d_in[23];
    const float* aw_w  = (const float*)d_in[24];
    const float* aw_b  = (const float*)d_in[25];
    float* out = (float*)d_out;

    // ---- scratch carved from OUT (free until the final pred GEMM, which
    //      overwrites every element of out[0, B*TD*V)) ----
    float* gemb  = out;                                   // B*TD*4096 = 9,961,472 f
    float* gpart = out + (size_t)B * TD * 4096;           // 4*128*5120 = 2,621,440 f
    // total 12.58M < B*TD*V = 24.32M floats

    // ---- workspace carve (floats; every region multiple of 4 floats) ----
    float* ws = (float*)d_ws;
    size_t off = 0;
    auto alloc = [&](size_t n) { float* p = ws + off; off += n; return p; };
    // zero region: 6 f32 states + xtd + xlg + xar (contiguous)
    float* h1   = alloc((size_t)BD);
    float* c1   = alloc((size_t)BD);
    float* h2   = alloc((size_t)BD);
    float* c2   = alloc((size_t)BD);
    float* arh  = alloc((size_t)BD);
    float* arc  = alloc((size_t)BD);
    unsigned short* xtd = (unsigned short*)alloc((size_t)B * 5120 / 2);
    unsigned short* xlg = (unsigned short*)alloc((size_t)B * 4096 / 2);
    unsigned short* xar = (unsigned short*)alloc((size_t)B * 2048 / 2);
    int zero_n = 6 * BD + (B * 5120 + B * 4096 + B * 2048) / 2;  // 1,507,328
    // rest
    float* gfa       = alloc((size_t)B * 4096);          // favg gate contribution
    float* prevh_all = alloc((size_t)(TD - 1) * BD);     // f32 h1 history (t=1..18)
    float* img_att   = alloc((size_t)B * NR * A_DIM);
    float* bias_td   = alloc(4096);
    float* bias_lg   = alloc(4096);
    float* bias_comb = alloc(5120);
    unsigned short* embs_bf  = (unsigned short*)alloc((size_t)B * TD * E / 2);
    unsigned short* feats_bf = (unsigned short*)alloc((size_t)B * NR * F / 2);
    unsigned short* Hout     = (unsigned short*)alloc((size_t)TD * BD / 2);       // h2 history
    unsigned short* Arout    = (unsigned short*)alloc((size_t)(TD - 1) * BD / 2); // arh history
    unsigned short* Wtd  = (unsigned short*)alloc((size_t)4096 * 5120 / 2);
    unsigned short* Wlg  = (unsigned short*)alloc((size_t)4096 * 4096 / 2);
    unsigned short* Wcomb = (unsigned short*)alloc((size_t)5120 * 2048 / 2);  // [War-il | Wad-pad]
    unsigned short* Wout = (unsigned short*)alloc((size_t)V * 1024 / 2);      // reads clamp to V-1
    unsigned short* Warl = (unsigned short*)alloc((size_t)1024 * 1024 / 2);
    unsigned short* Waf  = (unsigned short*)alloc((size_t)1024 * 2048 / 2);
    int* ip     = (int*)(ws + off);
    int* order  = ip; ip += B;
    int* active = ip; ip += TD + 1;
    int* seqs_s = ip; ip += B * T;

    float* loss_ptr = out + (size_t)B * TD * V + B * T + B;

    // ---- prologue ----
    k_sort_init<<<1, B, 0, stream>>>(sizes, sequences, order, active, seqs_s, out);
    k_zero<<<(zero_n + 255) / 256, 256, 0, stream>>>(h1, zero_n);
    k_favg<<<1024, 256, 0, stream>>>(feats, order, xtd);
    k_emb2bf<<<(B * TD * 128 + 255) / 256, 256, 0, stream>>>(emb, seqs_s, embs_bf);
    k_feats2bf<<<4608, 256, 0, stream>>>(feats, order, feats_bf);
    k_w2bf<<<10240, 256, 0, stream>>>(td_wi, 4096, td_wh, 1024, Wtd, (long)4096 * 640, 1);
    k_w2bf<<<8192, 256, 0, stream>>>(lg_wi, 3072, lg_wh, 1024, Wlg, (long)4096 * 512, 1);
    k_w2bf<<<4096, 256, 0, stream>>>(ar_wi, 1024, ar_wh, 1024, Wcomb, (long)4096 * 256, 1);
    k_w2bf<<<1024, 256, 0, stream>>>(ad_w, 1024, nullptr, 1024,
                                     Wcomb + (size_t)4096 * 2048, (long)1024 * 256, 0);
    k_w2bf<<<5000, 256, 0, stream>>>(out_w, 1024, nullptr, 0, Wout, (long)V * 128, 0);
    k_w2bf<<<512, 256, 0, stream>>>(arl_w, 1024, nullptr, 0, Warl, (long)1024 * 128, 0);
    k_w2bf<<<1024, 256, 0, stream>>>(af_w, 2048, nullptr, 0, Waf, (long)1024 * 256, 0);
    k_biasint<<<16, 256, 0, stream>>>(td_bi, td_bh, nullptr, bias_td, 4096);
    k_biasint<<<16, 256, 0, stream>>>(lg_bi, lg_bh, nullptr, bias_lg, 4096);
    k_biasint<<<20, 256, 0, stream>>>(ar_bi, ar_bh, ad_b, bias_comb, 5120);
    // img_att = feats_bf @ Waf^T + af_b   [4608 x 1024], NT=4 (N-width 64)
    k_gemm<4><<<dim3(16, 36), 256, 0, stream>>>(
        feats_bf, 2048, Waf, 2048, 2048, af_b,
        img_att, 1024, 1024, 0, nullptr, nullptr, nullptr);
    // gfa = favg @ Wtd[:,1024:3072]^T  (constant across t)  [128 x 4096]
    k_gemm<2><<<dim3(128, 1), 256, 0, stream>>>(
        xtd + 1024, 5120, Wtd + 1024, 5120, 2048, nullptr,
        gfa, 4096, 4096, 0, nullptr, nullptr, nullptr);
    // gemb = embs @ Wtd[:,3072:4096]^T for all t  [2432 x 4096], row m=b*TD+t
    k_gemm<2><<<dim3(128, TD), 256, 0, stream>>>(
        embs_bf, 1024, Wtd + 3072, 5120, 1024, nullptr,
        gemb, 4096, 4096, 0, nullptr, nullptr, nullptr);

    // ---- timestep loop (6 dispatches each) ----
    for (int t = 0; t < TD; ++t) {
        const int* actp = active + t;
        // td gates, in-loop K-regions only (h2 cols [0,1024), h1 cols [4096,5120)):
        // mode 6, Ksub=512, offsets {0,512,4096,4608} -> 4 partials
        k_gemm<2><<<dim3(128, 4), 256, 0, stream>>>(
            xtd, 5120, Wtd, 5120, 512, nullptr,
            gpart, 4096, 4096, 6, nullptr, nullptr, nullptr);
        k_lstm4<<<512, 256, 0, stream>>>(gpart, 4096, 4, bias_td,
            gfa, gemb + (size_t)t * 4096, TD * 4096,
            h1, c1, actp,
            (t > 0) ? prevh_all + (size_t)(t - 1) * BD : nullptr,
            xtd + 4096, 5120, xlg + 2048, 4096, xar, 2048);
        // combined ARNet gates + attention projection: split-K=4 (Ksub=512)
        k_gemm<2><<<dim3(160, 4), 256, 0, stream>>>(
            xar, 2048, Wcomb, 2048, 512, nullptr,
            gpart, 5120, 5120, 4, nullptr, nullptr, nullptr);
        // fused: h1a sum + attention + ARNet LSTM update
        k_attn_ar<<<B, 256, 0, stream>>>(
            gpart, bias_comb, img_att, aw_w, aw_b, feats_bf, xlg,
            arh, arc, actp, xar + 1024,
            (t > 0) ? Arout + (size_t)(t - 1) * BD : (unsigned short*)nullptr);
        // language LSTM gates: split-K=4 (Ksub=1024) -> 4 partials
        k_gemm<2><<<dim3(128, 4), 256, 0, stream>>>(
            xlg, 4096, Wlg, 4096, 1024, nullptr,
            gpart, 4096, 4096, 4, nullptr, nullptr, nullptr);
        k_lstm4<<<512, 256, 0, stream>>>(gpart, 4096, 4, bias_lg,
            nullptr, nullptr, 0,
            h2, c2, actp, nullptr,
            xtd, 5120, xlg + 3072, 4096, Hout + (size_t)t * BD, 1024);
    }

    // ---- deferred batched GEMMs ----
    // ARNet loss over t=1..18: (Arout @ Warl^T + arl_b - prevh_all)^2 masked
    k_gemm<2><<<dim3(32, TD - 1), 256, 0, stream>>>(
        Arout, 1024, Warl, 1024, 1024, arl_b,
        nullptr, 0, 1024, 1, prevh_all, active + 1, loss_ptr);
    // preds for all timesteps: [19*128 x 1024] @ Wout^T -> out[b][t][v]
    // NT=4 (N-width 64), grid (157 panels, 19 t). Overwrites the out-scratch.
    k_gemm<4><<<dim3((V + 63) / 64, TD), 256, 0, stream>>>(
        Hout, 1024, Wout, 1024, 1024, out_b,
        out, 0, V, 3, nullptr, active, nullptr);
}